// Round 7
// baseline (1843.752 us; speedup 1.0000x reference)
//
#include <hip/hip_runtime.h>
#include <math.h>

// Problem constants (B=4, N=1024, D=1024, H=2048, E=8)
#define T_TOK 4096
#define DIM   1024
#define HID   2048
#define NE    8
#define TMM   128   // M tile (tokens)
#define BK    64    // K chunk (bf16)
#define GATE_BLOCKS (T_TOK / 4)
#define GRID_BLKS 1024
#define PREP_IDS (8192 + GATE_BLOCKS + T_TOK)   // transposes + gate + xconv = 13312

typedef unsigned int  u32;
typedef unsigned short u16;
typedef __attribute__((ext_vector_type(8))) short bf16x8;  // 8 bf16 in 4 VGPRs
typedef __attribute__((ext_vector_type(8))) unsigned short u16x8;
typedef __attribute__((ext_vector_type(4))) float f32x4;

__device__ __forceinline__ float gelu_exact(float v) {
    return 0.5f * v * (1.0f + erff(v * 0.70710678118654752440f));
}

// tanh-form gelu: max abs err vs exact ~1e-3; one v_exp instead of erff poly
__device__ __forceinline__ float gelu_fast(float x) {
    float u = 1.5957691216057308f * (x + 0.044715f * x * x * x); // 2*0.79788456
    float e = __expf(u);                  // exp(2u')
    float t = 1.f - 2.f / (e + 1.f);      // tanh(u')
    return 0.5f * x * (1.f + t);
}

__device__ __forceinline__ u16 f2bf(float v) {
    u32 u = __float_as_uint(v);
    u32 r = (u + 0x7FFFu + ((u >> 16) & 1u)) >> 16;   // RNE
    return (u16)r;
}

// async global->LDS, 16B per lane; lds dest = wave-uniform base + lane*16;
// global source address is PER-LANE (indirection allowed).
__device__ __forceinline__ void gld_lds16(const void* g, void* l) {
    __builtin_amdgcn_global_load_lds(
        (const __attribute__((address_space(1))) u32*)g,
        (__attribute__((address_space(3))) u32*)l,
        16, 0, 0);
}

// ---------------------------------------------------------------------------
// Manual grid barrier (sense-reversal, device-scope atomics + threadfence).
// Works under ordinary launch (graph-capture-safe, unlike cooperative API).
// Release: __syncthreads drains stores to local L2 (vmcnt 0); threadfence
// (agent) writes back L2.  Acquire: RELEASE gen-bump / ACQUIRE spin load +
// threadfence invalidates L1/L2 before subsequent reads.
// Requires all gridDim.x blocks co-resident: LDS 32768 -> 5/CU,
// launch_bounds(256,4) -> VGPR<=128 -> 4/CU; grid = 4 x 256 CU = 1024.
// ---------------------------------------------------------------------------
__device__ __forceinline__ void grid_barrier(int* cnt, int* gen) {
    __syncthreads();
    if (threadIdx.x == 0) {
        __threadfence();
        const int g = __hip_atomic_load(gen, __ATOMIC_RELAXED,
                                        __HIP_MEMORY_SCOPE_AGENT);
        const int a = __hip_atomic_fetch_add(cnt, 1, __ATOMIC_ACQ_REL,
                                             __HIP_MEMORY_SCOPE_AGENT);
        if (a == (int)gridDim.x - 1) {
            __hip_atomic_store(cnt, 0, __ATOMIC_RELAXED,
                               __HIP_MEMORY_SCOPE_AGENT);
            __hip_atomic_fetch_add(gen, 1, __ATOMIC_RELEASE,
                                   __HIP_MEMORY_SCOPE_AGENT);
        } else {
            while (__hip_atomic_load(gen, __ATOMIC_ACQUIRE,
                                     __HIP_MEMORY_SCOPE_AGENT) == g)
                __builtin_amdgcn_s_sleep(8);
        }
        __threadfence();
    }
    __syncthreads();
}

// 64x64 transpose+convert tile: float4 loads, ushort8 (16B) stores.
__device__ __forceinline__ void transpose_body(
    const float* __restrict__ in, u16* __restrict__ out, int R, int C,
    int bx, int by, int bz, float (*tile)[65])
{
    const float* src = in  + (size_t)bz * R * C;
    u16*         dst = out + (size_t)bz * R * C;
    const int c0 = bx * 64, r0 = by * 64;
    const int th = threadIdx.x;

    const int tr  = th >> 4;
    const int tc4 = (th & 15) * 4;
    #pragma unroll
    for (int i = 0; i < 4; i++) {
        const int r = tr + i * 16;
        float4 v = *(const float4*)&src[(size_t)(r0 + r) * C + c0 + tc4];
        tile[r][tc4 + 0] = v.x; tile[r][tc4 + 1] = v.y;
        tile[r][tc4 + 2] = v.z; tile[r][tc4 + 3] = v.w;
    }
    __syncthreads();
    const int cc  = th >> 3;           // 0..31
    const int rr8 = (th & 7) * 8;      // 0..56
    #pragma unroll
    for (int i = 0; i < 2; i++) {
        const int c = cc + i * 32;
        u16x8 o;
        #pragma unroll
        for (int j = 0; j < 8; j++) o[j] = f2bf(tile[rr8 + j][c]);
        *(u16x8*)&dst[(size_t)(c0 + c) * R + r0 + rr8] = o;
    }
}

// ---------------------------------------------------------------------------
// ONE persistent kernel, 1024 blocks x 256 thr, 5 phases w/ manual barriers:
//  1) w1/w2 transpose->bf16 + gate + x->bf16           (grid-stride, 13 iters)
//  2) route: plan + scatter (block 0, LDS cursors)
//  3) ffn1: 128x128 MFMA tiles, 640 units (1/block), A via sorted_tok indir
//  4) ffn2: 128x128 MFMA tiles, 320 units
//  5) RMSNorm + GeLU (grid-stride)
// ---------------------------------------------------------------------------
__global__ __launch_bounds__(256, 4) void moe_mega(
    const float* __restrict__ x, const float* __restrict__ gw,
    const float* __restrict__ gb, const float* __restrict__ w1,
    const float* __restrict__ b1, const float* __restrict__ w2,
    const float* __restrict__ b2, const float* __restrict__ gamma,
    u16* __restrict__ w1t, u16* __restrict__ w2t, u16* __restrict__ xbf,
    u16* __restrict__ h_buf, float* __restrict__ top_val,
    int* __restrict__ top_idx, float* __restrict__ partial_imp,
    int* __restrict__ partial_cnt, int* __restrict__ sorted_tok,
    int* __restrict__ tile_e, int* __restrict__ tile_s,
    int* __restrict__ tile_rows, int* __restrict__ ntiles,
    int* bar_cnt, int* bar_gen,
    float* __restrict__ yout, float* __restrict__ loss_out)
{
    __shared__ __align__(16) char smem[32768];
    const int th = threadIdx.x;

    // ================= phase 1: transposes + gate + x->bf16 =================
    {
        float (*tile)[65] = (float (*)[65])smem;          // 16640 B
        float* s_imp = (float*)(smem + 16640);            // 32 B
        int*   s_cnt = (int*)  (smem + 16672);            // 32 B
        for (int id = blockIdx.x; id < PREP_IDS; id += GRID_BLKS) {
            if (id < 4096) {
                // w1 [E][D][H] -> w1t [E][H][D]: R=DIM, C=HID
                transpose_body(w1, w1t, DIM, HID, id & 31, (id >> 5) & 15,
                               id >> 9, tile);
            } else if (id < 8192) {
                // w2 [E][H][D] -> w2t [E][D][H]: R=HID, C=DIM
                const int i2 = id - 4096;
                transpose_body(w2, w2t, HID, DIM, i2 & 15, (i2 >> 4) & 31,
                               i2 >> 9, tile);
            } else if (id < 8192 + GATE_BLOCKS) {
                // ---- gate: 4 tokens per virtual block ----
                const int g = id - 8192;
                if (th < NE) { s_imp[th] = 0.f; s_cnt[th] = 0; }
                __syncthreads();
                const int wave = th >> 6, lane = th & 63;
                const int t = g * 4 + wave;
                float acc[NE];
                #pragma unroll
                for (int e = 0; e < NE; e++) acc[e] = 0.f;
                const float* xr = x + (size_t)t * DIM;
                #pragma unroll 4
                for (int k = lane; k < DIM; k += 64) {
                    float xv = xr[k];
                    const float* gp = gw + (size_t)k * NE;
                    float4 g0 = *(const float4*)gp;
                    float4 g1 = *(const float4*)(gp + 4);
                    acc[0] += xv * g0.x; acc[1] += xv * g0.y;
                    acc[2] += xv * g0.z; acc[3] += xv * g0.w;
                    acc[4] += xv * g1.x; acc[5] += xv * g1.y;
                    acc[6] += xv * g1.z; acc[7] += xv * g1.w;
                }
                #pragma unroll
                for (int e = 0; e < NE; e++) {
                    #pragma unroll
                    for (int off = 32; off > 0; off >>= 1)
                        acc[e] += __shfl_down(acc[e], off, 64);
                }
                if (lane == 0) {
                    float l[NE];
                    float m = -1e30f;
                    #pragma unroll
                    for (int e = 0; e < NE; e++) { l[e] = acc[e] + gb[e]; m = fmaxf(m, l[e]); }
                    float s = 0.f;
                    #pragma unroll
                    for (int e = 0; e < NE; e++) { l[e] = expf(l[e] - m); s += l[e]; }
                    float inv = 1.f / s;
                    int bi = 0; float bv = -1.f;
                    #pragma unroll
                    for (int e = 0; e < NE; e++) {
                        float p = l[e] * inv;
                        atomicAdd(&s_imp[e], p);          // LDS atomic
                        if (p > bv) { bv = p; bi = e; }   // strict > => first argmax
                    }
                    top_val[t] = bv;
                    top_idx[t] = bi;
                    atomicAdd(&s_cnt[bi], 1);
                }
                __syncthreads();
                if (th < NE) {
                    partial_imp[g * NE + th] = s_imp[th];
                    partial_cnt[g * NE + th] = s_cnt[th];
                }
            } else {
                // ---- x fp32 -> bf16 (token order; ffn1 reads via indirection) ----
                const int row = id - (8192 + GATE_BLOCKS);
                const float* src = x + (size_t)row * DIM;
                u16* dst = xbf + (size_t)row * DIM;
                const int i = th * 4;
                float4 v = *(const float4*)&src[i];
                ushort4 o;
                o.x = f2bf(v.x); o.y = f2bf(v.y); o.z = f2bf(v.z); o.w = f2bf(v.w);
                *(ushort4*)&dst[i] = o;
            }
            __syncthreads();   // LDS reuse across grid-stride iterations
        }
    }
    grid_barrier(bar_cnt, bar_gen);

    // ================= phase 2: route (plan + scatter), block 0 =============
    if (blockIdx.x == 0) {
        float (*rimp)[NE] = (float (*)[NE])smem;          // 1024 B
        int   (*rcnt)[NE] = (int (*)[NE])(smem + 1024);   // 1024 B
        int* s_off = (int*)(smem + 2048);
        int* s_cur = (int*)(smem + 2080);
        const int e = th & 7, chunk = th >> 3;   // 32 chunks of 32 gate blocks
        float si = 0.f; int sc = 0;
        #pragma unroll 8
        for (int i = 0; i < GATE_BLOCKS / 32; i++) {
            const int b = chunk * (GATE_BLOCKS / 32) + i;
            si += partial_imp[b * NE + e];
            sc += partial_cnt[b * NE + e];
        }
        rimp[chunk][e] = si;
        rcnt[chunk][e] = sc;
        __syncthreads();
        if (th < NE) {
            float s = 0.f; int c = 0;
            for (int i = 0; i < 32; i++) { s += rimp[i][th]; c += rcnt[i][th]; }
            rimp[0][th] = s;
            rcnt[0][th] = c;
            s_cur[th] = 0;
        }
        __syncthreads();
        if (th == 0) {
            int off = 0, nt = 0;
            for (int ee = 0; ee < NE; ee++) {
                s_off[ee] = off;
                const int c = rcnt[0][ee];
                for (int s = 0; s < c; s += TMM) {
                    tile_e[nt] = ee;
                    tile_s[nt] = off + s;
                    tile_rows[nt] = min(TMM, c - s);
                    nt++;
                }
                off += c;
            }
            *ntiles = nt;   // <= 40

            float mean = 0.f;
            for (int ee = 0; ee < NE; ee++) mean += rimp[0][ee];
            mean *= (1.0f / NE);
            float var = 0.f;
            for (int ee = 0; ee < NE; ee++) { float d = rimp[0][ee] - mean; var += d * d; }
            var *= (1.0f / (NE - 1));
            loss_out[0] = var / (mean * mean + 1e-10f);
        }
        __syncthreads();
        // scatter: 16 rounds x 256 tokens, LDS cursors
        #pragma unroll 4
        for (int r = 0; r < T_TOK / 256; r++) {
            const int t  = r * 256 + th;
            const int te = top_idx[t];
            const int rank = atomicAdd(&s_cur[te], 1);
            sorted_tok[s_off[te] + rank] = t;
        }
    }
    grid_barrier(bar_cnt, bar_gen);

    // ================= phase 3: ffn1 (640 units: tile fastest) ==============
    {
        const int u = blockIdx.x;
        if (u < 40 * (HID / 128)) {
            const int tile  = u % 40;
            const int nbase = (u / 40) * 128;
            const int nt = *ntiles;
            if (tile < nt) {
                u16* As = (u16*)smem;            // 16 KB
                u16* Bs = (u16*)(smem + 16384);  // 16 KB
                const int e     = tile_e[tile];
                const int sbase = tile_s[tile];
                const int rows  = tile_rows[tile];
                const int w  = th >> 6;
                const int l  = th & 63;
                const int wm = w >> 1, wn = w & 1;
                const int lr = l >> 3;
                const int lcs = ((l & 7) ^ lr) * 8;    // swizzled fetch offset

                const u16* aptr[4];
                #pragma unroll
                for (int c = 0; c < 4; c++) {
                    int srow = sbase + w * 32 + c * 8 + lr;
                    if (srow > T_TOK - 1) srow = T_TOK - 1;
                    const int tok = sorted_tok[srow];
                    aptr[c] = xbf + (size_t)tok * DIM + lcs;
                }
                const u16* wb = w1t + (size_t)e * HID * DIM + (size_t)nbase * DIM;
                const u16* bptr[4];
                #pragma unroll
                for (int c = 0; c < 4; c++)
                    bptr[c] = wb + (size_t)(w * 32 + c * 8 + lr) * DIM + lcs;

                f32x4 acc[4][4] = {};

                for (int k0 = 0; k0 < DIM; k0 += BK) {
                    __syncthreads();
                    #pragma unroll
                    for (int c = 0; c < 4; c++)
                        gld_lds16(aptr[c] + k0, &As[(w * 32 + c * 8) * BK]);
                    #pragma unroll
                    for (int c = 0; c < 4; c++)
                        gld_lds16(bptr[c] + k0, &Bs[(w * 32 + c * 8) * BK]);
                    __syncthreads();
                    #pragma unroll
                    for (int ks = 0; ks < 2; ks++) {
                        const int ko = ((ks * 4 + (l >> 4)) ^ (l & 7)) * 8;
                        bf16x8 af[4], bfr[4];
                        #pragma unroll
                        for (int i = 0; i < 4; i++)
                            af[i]  = *(const bf16x8*)&As[(wm * 64 + i * 16 + (l & 15)) * BK + ko];
                        #pragma unroll
                        for (int i = 0; i < 4; i++)
                            bfr[i] = *(const bf16x8*)&Bs[(wn * 64 + i * 16 + (l & 15)) * BK + ko];
                        #pragma unroll
                        for (int mi = 0; mi < 4; mi++)
                            #pragma unroll
                            for (int ni = 0; ni < 4; ni++)
                                acc[mi][ni] = __builtin_amdgcn_mfma_f32_16x16x32_bf16(
                                    af[mi], bfr[ni], acc[mi][ni], 0, 0, 0);
                    }
                }

                const int col = l & 15, quad = l >> 4;
                #pragma unroll
                for (int ni = 0; ni < 4; ni++) {
                    const int n = nbase + wn * 64 + ni * 16 + col;
                    const float bias = b1[e * HID + n];
                    #pragma unroll
                    for (int mi = 0; mi < 4; mi++) {
                        #pragma unroll
                        for (int r = 0; r < 4; r++) {
                            const int m = wm * 64 + mi * 16 + quad * 4 + r;
                            if (m < rows) {
                                float v = acc[mi][ni][r] + bias;
                                h_buf[(size_t)(sbase + m) * HID + n] = f2bf(gelu_fast(v));
                            }
                        }
                    }
                }
            }
        }
    }
    grid_barrier(bar_cnt, bar_gen);

    // ================= phase 4: ffn2 (320 units: tile fastest) ==============
    {
        const int u = blockIdx.x;
        if (u < 40 * (DIM / 128)) {
            const int tile  = u % 40;
            const int nbase = (u / 40) * 128;
            const int nt = *ntiles;
            if (tile < nt) {
                u16* As = (u16*)smem;
                u16* Bs = (u16*)(smem + 16384);
                const int e     = tile_e[tile];
                const int sbase = tile_s[tile];
                const int rows  = tile_rows[tile];
                const int w  = th >> 6;
                const int l  = th & 63;
                const int wm = w >> 1, wn = w & 1;
                const int lr = l >> 3;
                const int lcs = ((l & 7) ^ lr) * 8;

                const u16* aptr[4];
                #pragma unroll
                for (int c = 0; c < 4; c++) {
                    int srow = sbase + w * 32 + c * 8 + lr;
                    if (srow > T_TOK - 1) srow = T_TOK - 1;
                    aptr[c] = h_buf + (size_t)srow * HID + lcs;
                }
                const u16* wb = w2t + (size_t)e * DIM * HID + (size_t)nbase * HID;
                const u16* bptr[4];
                #pragma unroll
                for (int c = 0; c < 4; c++)
                    bptr[c] = wb + (size_t)(w * 32 + c * 8 + lr) * HID + lcs;

                f32x4 acc[4][4] = {};

                for (int k0 = 0; k0 < HID; k0 += BK) {
                    __syncthreads();
                    #pragma unroll
                    for (int c = 0; c < 4; c++)
                        gld_lds16(aptr[c] + k0, &As[(w * 32 + c * 8) * BK]);
                    #pragma unroll
                    for (int c = 0; c < 4; c++)
                        gld_lds16(bptr[c] + k0, &Bs[(w * 32 + c * 8) * BK]);
                    __syncthreads();
                    #pragma unroll
                    for (int ks = 0; ks < 2; ks++) {
                        const int ko = ((ks * 4 + (l >> 4)) ^ (l & 7)) * 8;
                        bf16x8 af[4], bfr[4];
                        #pragma unroll
                        for (int i = 0; i < 4; i++)
                            af[i]  = *(const bf16x8*)&As[(wm * 64 + i * 16 + (l & 15)) * BK + ko];
                        #pragma unroll
                        for (int i = 0; i < 4; i++)
                            bfr[i] = *(const bf16x8*)&Bs[(wn * 64 + i * 16 + (l & 15)) * BK + ko];
                        #pragma unroll
                        for (int mi = 0; mi < 4; mi++)
                            #pragma unroll
                            for (int ni = 0; ni < 4; ni++)
                                acc[mi][ni] = __builtin_amdgcn_mfma_f32_16x16x32_bf16(
                                    af[mi], bfr[ni], acc[mi][ni], 0, 0, 0);
                    }
                }

                const int col = l & 15, quad = l >> 4;
                float bias[4];
                #pragma unroll
                for (int ni = 0; ni < 4; ni++)
                    bias[ni] = b2[e * DIM + nbase + wn * 64 + ni * 16 + col];

                #pragma unroll
                for (int mi = 0; mi < 4; mi++) {
                    #pragma unroll
                    for (int r = 0; r < 4; r++) {
                        const int m = wm * 64 + mi * 16 + quad * 4 + r;
                        if (m < rows) {
                            const int t = sorted_tok[sbase + m];
                            const float tv = top_val[t];
                            #pragma unroll
                            for (int ni = 0; ni < 4; ni++) {
                                const int n = nbase + wn * 64 + ni * 16 + col;
                                float v = acc[mi][ni][r] + bias[ni];
                                yout[(size_t)t * DIM + n] = x[(size_t)t * DIM + n] + v * tv;
                            }
                        }
                    }
                }
            }
        }
    }
    grid_barrier(bar_cnt, bar_gen);

    // ================= phase 5: RMSNorm + exact GeLU ========================
    {
        float* red = (float*)smem;
        for (int t = blockIdx.x; t < T_TOK; t += GRID_BLKS) {
            float* row = yout + (size_t)t * DIM;
            float4 v = *(const float4*)&row[th * 4];
            float ss = v.x * v.x + v.y * v.y + v.z * v.z + v.w * v.w;

            const int lane = th & 63, wave = th >> 6;
            #pragma unroll
            for (int off = 32; off > 0; off >>= 1) ss += __shfl_down(ss, off, 64);
            if (lane == 0) red[wave] = ss;
            __syncthreads();
            float total = red[0] + red[1] + red[2] + red[3];

            float nrm = sqrtf(total);
            float scale = 32.0f / fmaxf(nrm, 1e-12f);   // sqrt(1024) = 32

            float4 g = *(const float4*)&gamma[th * 4];
            float4 o;
            o.x = gelu_exact(v.x * scale * g.x);
            o.y = gelu_exact(v.y * scale * g.y);
            o.z = gelu_exact(v.z * scale * g.z);
            o.w = gelu_exact(v.w * scale * g.w);
            *(float4*)&row[th * 4] = o;
            __syncthreads();   // red reuse across iterations
        }
    }
}

// ---------------------------------------------------------------------------
extern "C" void kernel_launch(void* const* d_in, const int* in_sizes, int n_in,
                              void* d_out, int out_size, void* d_ws, size_t ws_size,
                              hipStream_t stream) {
    const float* x      = (const float*)d_in[0];
    const float* gate_w = (const float*)d_in[1];
    const float* gate_b = (const float*)d_in[2];
    const float* w1     = (const float*)d_in[3];
    const float* b1     = (const float*)d_in[4];
    const float* w2     = (const float*)d_in[5];
    const float* b2     = (const float*)d_in[6];
    const float* gamma  = (const float*)d_in[7];

    float* out  = (float*)d_out;                  // [T*D] y, then [1] loss
    float* loss = out + (size_t)T_TOK * DIM;

    char* ws = (char*)d_ws;
    float* top_val     = (float*)(ws + 0);         // 4096 f
    int*   top_idx     = (int*)  (ws + 16384);     // 4096 i
    int*   sorted_tok  = (int*)  (ws + 32768);     // 4096 i
    int*   bar_cnt     = (int*)  (ws + 49152);     // 1 i (zeroed per launch)
    int*   bar_gen     = (int*)  (ws + 49156);     // 1 i (zeroed per launch)
    int*   tile_e      = (int*)  (ws + 49664);     // 40 i
    int*   tile_s      = (int*)  (ws + 50176);     // 40 i
    int*   tile_rows   = (int*)  (ws + 50688);     // 40 i
    int*   ntiles      = (int*)  (ws + 51200);     // 1 i
    float* partial_imp = (float*)(ws + 65536);     // 1024*8 f = 32 KB
    int*   partial_cnt = (int*)  (ws + 98304);     // 1024*8 i = 32 KB
    u16*   xbf         = (u16*)  (ws + 131072);                      // 8 MiB
    u16*   h_buf       = (u16*)  (ws + 131072 + 8388608);            // 16 MiB
    u16*   w1t         = (u16*)  (ws + 131072 + 8388608 + 16777216);            // 32 MiB
    u16*   w2t         = (u16*)  (ws + 131072 + 8388608 + 16777216 + 33554432); // 32 MiB

    hipMemsetAsync(ws + 49152, 0, 8, stream);      // barrier state

    moe_mega<<<GRID_BLKS, 256, 0, stream>>>(
        x, gate_w, gate_b, w1, b1, w2, b2, gamma,
        w1t, w2t, xbf, h_buf, top_val, top_idx,
        partial_imp, partial_cnt, sorted_tok,
        tile_e, tile_s, tile_rows, ntiles,
        bar_cnt, bar_gen, out, loss);
}

// Round 8
// 1300.742 us; speedup vs baseline: 1.4175x; 1.4175x over previous
//
#include <hip/hip_runtime.h>
#include <math.h>

// Problem constants (B=4, N=1024, D=1024, H=2048, E=8)
#define T_TOK 4096
#define DIM   1024
#define HID   2048
#define NE    8
#define TMM   128   // M tile (tokens)
#define BK    64    // K chunk (bf16)
#define GATE_BLOCKS (T_TOK / 4)
#define GRID_BLKS 768   // 3 blocks/CU x 256 CU (VGPR-bound residency, see below)
#define PREP_IDS (8192 + GATE_BLOCKS + T_TOK)   // transposes + gate + xconv = 13312

typedef unsigned int  u32;
typedef unsigned short u16;
typedef __attribute__((ext_vector_type(8))) short bf16x8;  // 8 bf16 in 4 VGPRs
typedef __attribute__((ext_vector_type(8))) unsigned short u16x8;
typedef __attribute__((ext_vector_type(4))) float f32x4;

__device__ __forceinline__ float gelu_exact(float v) {
    return 0.5f * v * (1.0f + erff(v * 0.70710678118654752440f));
}

// tanh-form gelu: max abs err vs exact ~1e-3; one v_exp instead of erff poly
__device__ __forceinline__ float gelu_fast(float x) {
    float u = 1.5957691216057308f * (x + 0.044715f * x * x * x); // 2*0.79788456
    float e = __expf(u);                  // exp(2u')
    float t = 1.f - 2.f / (e + 1.f);      // tanh(u')
    return 0.5f * x * (1.f + t);
}

__device__ __forceinline__ u16 f2bf(float v) {
    u32 u = __float_as_uint(v);
    u32 r = (u + 0x7FFFu + ((u >> 16) & 1u)) >> 16;   // RNE
    return (u16)r;
}

// async global->LDS, 16B per lane; lds dest = wave-uniform base + lane*16;
// global source address is PER-LANE (indirection allowed).
__device__ __forceinline__ void gld_lds16(const void* g, void* l) {
    __builtin_amdgcn_global_load_lds(
        (const __attribute__((address_space(1))) u32*)g,
        (__attribute__((address_space(3))) u32*)l,
        16, 0, 0);
}

// ---------------------------------------------------------------------------
// Manual grid barrier (sense-reversal, device-scope atomics + threadfence).
// Works under ordinary launch (graph-capture-safe, unlike cooperative API --
// R6 failed silently; R7 passed with this barrier).
// Residency contract: launch_bounds(256,3) -> reg cap ~170 (R5 body needs
// 96 VGPR + 64 AGPR = 160, no spills) -> 3 blocks/CU by VGPR; LDS 32KB -> 5;
// grid = 3 x 256 CU = 768 co-resident guaranteed.
// ---------------------------------------------------------------------------
__device__ __forceinline__ void grid_barrier(int* cnt, int* gen) {
    __syncthreads();
    if (threadIdx.x == 0) {
        __threadfence();
        const int g = __hip_atomic_load(gen, __ATOMIC_RELAXED,
                                        __HIP_MEMORY_SCOPE_AGENT);
        const int a = __hip_atomic_fetch_add(cnt, 1, __ATOMIC_ACQ_REL,
                                             __HIP_MEMORY_SCOPE_AGENT);
        if (a == (int)gridDim.x - 1) {
            __hip_atomic_store(cnt, 0, __ATOMIC_RELAXED,
                               __HIP_MEMORY_SCOPE_AGENT);
            __hip_atomic_fetch_add(gen, 1, __ATOMIC_RELEASE,
                                   __HIP_MEMORY_SCOPE_AGENT);
        } else {
            while (__hip_atomic_load(gen, __ATOMIC_ACQUIRE,
                                     __HIP_MEMORY_SCOPE_AGENT) == g)
                __builtin_amdgcn_s_sleep(8);
        }
        __threadfence();
    }
    __syncthreads();
}

// 64x64 transpose+convert tile: float4 loads, ushort8 (16B) stores.
__device__ __forceinline__ void transpose_body(
    const float* __restrict__ in, u16* __restrict__ out, int R, int C,
    int bx, int by, int bz, float (*tile)[65])
{
    const float* src = in  + (size_t)bz * R * C;
    u16*         dst = out + (size_t)bz * R * C;
    const int c0 = bx * 64, r0 = by * 64;
    const int th = threadIdx.x;

    const int tr  = th >> 4;
    const int tc4 = (th & 15) * 4;
    #pragma unroll
    for (int i = 0; i < 4; i++) {
        const int r = tr + i * 16;
        float4 v = *(const float4*)&src[(size_t)(r0 + r) * C + c0 + tc4];
        tile[r][tc4 + 0] = v.x; tile[r][tc4 + 1] = v.y;
        tile[r][tc4 + 2] = v.z; tile[r][tc4 + 3] = v.w;
    }
    __syncthreads();
    const int cc  = th >> 3;           // 0..31
    const int rr8 = (th & 7) * 8;      // 0..56
    #pragma unroll
    for (int i = 0; i < 2; i++) {
        const int c = cc + i * 32;
        u16x8 o;
        #pragma unroll
        for (int j = 0; j < 8; j++) o[j] = f2bf(tile[rr8 + j][c]);
        *(u16x8*)&dst[(size_t)(c0 + c) * R + r0 + rr8] = o;
    }
}

// ---------------------------------------------------------------------------
// ONE persistent kernel, 768 blocks x 256 thr, 5 phases w/ manual barriers:
//  1) w1/w2 transpose->bf16 + gate + x->bf16           (grid-stride)
//  2) route: plan + scatter (block 0, LDS cursors)
//  3) ffn1: 128x128 MFMA tiles, 640 units (1/block), A via sorted_tok indir
//  4) ffn2: 128x128 MFMA tiles, 320 units
//  5) RMSNorm + GeLU (grid-stride)
// ---------------------------------------------------------------------------
__global__ __launch_bounds__(256, 3) void moe_mega(
    const float* __restrict__ x, const float* __restrict__ gw,
    const float* __restrict__ gb, const float* __restrict__ w1,
    const float* __restrict__ b1, const float* __restrict__ w2,
    const float* __restrict__ b2, const float* __restrict__ gamma,
    u16* __restrict__ w1t, u16* __restrict__ w2t, u16* __restrict__ xbf,
    u16* __restrict__ h_buf, float* __restrict__ top_val,
    int* __restrict__ top_idx, float* __restrict__ partial_imp,
    int* __restrict__ partial_cnt, int* __restrict__ sorted_tok,
    int* __restrict__ tile_e, int* __restrict__ tile_s,
    int* __restrict__ tile_rows, int* __restrict__ ntiles,
    int* bar_cnt, int* bar_gen,
    float* __restrict__ yout, float* __restrict__ loss_out)
{
    __shared__ __align__(16) char smem[32768];
    const int th = threadIdx.x;

    // ================= phase 1: transposes + gate + x->bf16 =================
    {
        float (*tile)[65] = (float (*)[65])smem;          // 16640 B
        float* s_imp = (float*)(smem + 16640);            // 32 B
        int*   s_cnt = (int*)  (smem + 16672);            // 32 B
        for (int id = blockIdx.x; id < PREP_IDS; id += GRID_BLKS) {
            if (id < 4096) {
                // w1 [E][D][H] -> w1t [E][H][D]: R=DIM, C=HID
                transpose_body(w1, w1t, DIM, HID, id & 31, (id >> 5) & 15,
                               id >> 9, tile);
            } else if (id < 8192) {
                // w2 [E][H][D] -> w2t [E][D][H]: R=HID, C=DIM
                const int i2 = id - 4096;
                transpose_body(w2, w2t, HID, DIM, i2 & 15, (i2 >> 4) & 31,
                               i2 >> 9, tile);
            } else if (id < 8192 + GATE_BLOCKS) {
                // ---- gate: 4 tokens per virtual block ----
                const int g = id - 8192;
                if (th < NE) { s_imp[th] = 0.f; s_cnt[th] = 0; }
                __syncthreads();
                const int wave = th >> 6, lane = th & 63;
                const int t = g * 4 + wave;
                float acc[NE];
                #pragma unroll
                for (int e = 0; e < NE; e++) acc[e] = 0.f;
                const float* xr = x + (size_t)t * DIM;
                #pragma unroll 4
                for (int k = lane; k < DIM; k += 64) {
                    float xv = xr[k];
                    const float* gp = gw + (size_t)k * NE;
                    float4 g0 = *(const float4*)gp;
                    float4 g1 = *(const float4*)(gp + 4);
                    acc[0] += xv * g0.x; acc[1] += xv * g0.y;
                    acc[2] += xv * g0.z; acc[3] += xv * g0.w;
                    acc[4] += xv * g1.x; acc[5] += xv * g1.y;
                    acc[6] += xv * g1.z; acc[7] += xv * g1.w;
                }
                #pragma unroll
                for (int e = 0; e < NE; e++) {
                    #pragma unroll
                    for (int off = 32; off > 0; off >>= 1)
                        acc[e] += __shfl_down(acc[e], off, 64);
                }
                if (lane == 0) {
                    float l[NE];
                    float m = -1e30f;
                    #pragma unroll
                    for (int e = 0; e < NE; e++) { l[e] = acc[e] + gb[e]; m = fmaxf(m, l[e]); }
                    float s = 0.f;
                    #pragma unroll
                    for (int e = 0; e < NE; e++) { l[e] = expf(l[e] - m); s += l[e]; }
                    float inv = 1.f / s;
                    int bi = 0; float bv = -1.f;
                    #pragma unroll
                    for (int e = 0; e < NE; e++) {
                        float p = l[e] * inv;
                        atomicAdd(&s_imp[e], p);          // LDS atomic
                        if (p > bv) { bv = p; bi = e; }   // strict > => first argmax
                    }
                    top_val[t] = bv;
                    top_idx[t] = bi;
                    atomicAdd(&s_cnt[bi], 1);
                }
                __syncthreads();
                if (th < NE) {
                    partial_imp[g * NE + th] = s_imp[th];
                    partial_cnt[g * NE + th] = s_cnt[th];
                }
            } else {
                // ---- x fp32 -> bf16 (token order; ffn1 reads via indirection) ----
                const int row = id - (8192 + GATE_BLOCKS);
                const float* src = x + (size_t)row * DIM;
                u16* dst = xbf + (size_t)row * DIM;
                const int i = th * 4;
                float4 v = *(const float4*)&src[i];
                ushort4 o;
                o.x = f2bf(v.x); o.y = f2bf(v.y); o.z = f2bf(v.z); o.w = f2bf(v.w);
                *(ushort4*)&dst[i] = o;
            }
            __syncthreads();   // LDS reuse across grid-stride iterations
        }
    }
    grid_barrier(bar_cnt, bar_gen);

    // ================= phase 2: route (plan + scatter), block 0 =============
    if (blockIdx.x == 0) {
        float (*rimp)[NE] = (float (*)[NE])smem;          // 1024 B
        int   (*rcnt)[NE] = (int (*)[NE])(smem + 1024);   // 1024 B
        int* s_off = (int*)(smem + 2048);
        int* s_cur = (int*)(smem + 2080);
        const int e = th & 7, chunk = th >> 3;   // 32 chunks of 32 gate blocks
        float si = 0.f; int sc = 0;
        #pragma unroll 8
        for (int i = 0; i < GATE_BLOCKS / 32; i++) {
            const int b = chunk * (GATE_BLOCKS / 32) + i;
            si += partial_imp[b * NE + e];
            sc += partial_cnt[b * NE + e];
        }
        rimp[chunk][e] = si;
        rcnt[chunk][e] = sc;
        __syncthreads();
        if (th < NE) {
            float s = 0.f; int c = 0;
            for (int i = 0; i < 32; i++) { s += rimp[i][th]; c += rcnt[i][th]; }
            rimp[0][th] = s;
            rcnt[0][th] = c;
            s_cur[th] = 0;
        }
        __syncthreads();
        if (th == 0) {
            int off = 0, nt = 0;
            for (int ee = 0; ee < NE; ee++) {
                s_off[ee] = off;
                const int c = rcnt[0][ee];
                for (int s = 0; s < c; s += TMM) {
                    tile_e[nt] = ee;
                    tile_s[nt] = off + s;
                    tile_rows[nt] = min(TMM, c - s);
                    nt++;
                }
                off += c;
            }
            *ntiles = nt;   // <= 40

            float mean = 0.f;
            for (int ee = 0; ee < NE; ee++) mean += rimp[0][ee];
            mean *= (1.0f / NE);
            float var = 0.f;
            for (int ee = 0; ee < NE; ee++) { float d = rimp[0][ee] - mean; var += d * d; }
            var *= (1.0f / (NE - 1));
            loss_out[0] = var / (mean * mean + 1e-10f);
        }
        __syncthreads();
        // scatter: 16 rounds x 256 tokens, LDS cursors
        #pragma unroll 4
        for (int r = 0; r < T_TOK / 256; r++) {
            const int t  = r * 256 + th;
            const int te = top_idx[t];
            const int rank = atomicAdd(&s_cur[te], 1);
            sorted_tok[s_off[te] + rank] = t;
        }
    }
    grid_barrier(bar_cnt, bar_gen);

    // ================= phase 3: ffn1 (640 units: tile fastest) ==============
    {
        const int u = blockIdx.x;
        if (u < 40 * (HID / 128)) {
            const int tile  = u % 40;
            const int nbase = (u / 40) * 128;
            const int nt = *ntiles;
            if (tile < nt) {
                u16* As = (u16*)smem;            // 16 KB
                u16* Bs = (u16*)(smem + 16384);  // 16 KB
                const int e     = tile_e[tile];
                const int sbase = tile_s[tile];
                const int rows  = tile_rows[tile];
                const int w  = th >> 6;
                const int l  = th & 63;
                const int wm = w >> 1, wn = w & 1;
                const int lr = l >> 3;
                const int lcs = ((l & 7) ^ lr) * 8;    // swizzled fetch offset

                const u16* aptr[4];
                #pragma unroll
                for (int c = 0; c < 4; c++) {
                    int srow = sbase + w * 32 + c * 8 + lr;
                    if (srow > T_TOK - 1) srow = T_TOK - 1;
                    const int tok = sorted_tok[srow];
                    aptr[c] = xbf + (size_t)tok * DIM + lcs;
                }
                const u16* wb = w1t + (size_t)e * HID * DIM + (size_t)nbase * DIM;
                const u16* bptr[4];
                #pragma unroll
                for (int c = 0; c < 4; c++)
                    bptr[c] = wb + (size_t)(w * 32 + c * 8 + lr) * DIM + lcs;

                f32x4 acc[4][4] = {};

                for (int k0 = 0; k0 < DIM; k0 += BK) {
                    __syncthreads();
                    #pragma unroll
                    for (int c = 0; c < 4; c++)
                        gld_lds16(aptr[c] + k0, &As[(w * 32 + c * 8) * BK]);
                    #pragma unroll
                    for (int c = 0; c < 4; c++)
                        gld_lds16(bptr[c] + k0, &Bs[(w * 32 + c * 8) * BK]);
                    __syncthreads();
                    #pragma unroll
                    for (int ks = 0; ks < 2; ks++) {
                        const int ko = ((ks * 4 + (l >> 4)) ^ (l & 7)) * 8;
                        bf16x8 af[4], bfr[4];
                        #pragma unroll
                        for (int i = 0; i < 4; i++)
                            af[i]  = *(const bf16x8*)&As[(wm * 64 + i * 16 + (l & 15)) * BK + ko];
                        #pragma unroll
                        for (int i = 0; i < 4; i++)
                            bfr[i] = *(const bf16x8*)&Bs[(wn * 64 + i * 16 + (l & 15)) * BK + ko];
                        #pragma unroll
                        for (int mi = 0; mi < 4; mi++)
                            #pragma unroll
                            for (int ni = 0; ni < 4; ni++)
                                acc[mi][ni] = __builtin_amdgcn_mfma_f32_16x16x32_bf16(
                                    af[mi], bfr[ni], acc[mi][ni], 0, 0, 0);
                    }
                }

                const int col = l & 15, quad = l >> 4;
                #pragma unroll
                for (int ni = 0; ni < 4; ni++) {
                    const int n = nbase + wn * 64 + ni * 16 + col;
                    const float bias = b1[e * HID + n];
                    #pragma unroll
                    for (int mi = 0; mi < 4; mi++) {
                        #pragma unroll
                        for (int r = 0; r < 4; r++) {
                            const int m = wm * 64 + mi * 16 + quad * 4 + r;
                            if (m < rows) {
                                float v = acc[mi][ni][r] + bias;
                                h_buf[(size_t)(sbase + m) * HID + n] = f2bf(gelu_fast(v));
                            }
                        }
                    }
                }
            }
        }
    }
    grid_barrier(bar_cnt, bar_gen);

    // ================= phase 4: ffn2 (320 units: tile fastest) ==============
    {
        const int u = blockIdx.x;
        if (u < 40 * (DIM / 128)) {
            const int tile  = u % 40;
            const int nbase = (u / 40) * 128;
            const int nt = *ntiles;
            if (tile < nt) {
                u16* As = (u16*)smem;
                u16* Bs = (u16*)(smem + 16384);
                const int e     = tile_e[tile];
                const int sbase = tile_s[tile];
                const int rows  = tile_rows[tile];
                const int w  = th >> 6;
                const int l  = th & 63;
                const int wm = w >> 1, wn = w & 1;
                const int lr = l >> 3;
                const int lcs = ((l & 7) ^ lr) * 8;

                const u16* aptr[4];
                #pragma unroll
                for (int c = 0; c < 4; c++) {
                    int srow = sbase + w * 32 + c * 8 + lr;
                    if (srow > T_TOK - 1) srow = T_TOK - 1;
                    aptr[c] = h_buf + (size_t)srow * HID + lcs;
                }
                const u16* wb = w2t + (size_t)e * DIM * HID + (size_t)nbase * HID;
                const u16* bptr[4];
                #pragma unroll
                for (int c = 0; c < 4; c++)
                    bptr[c] = wb + (size_t)(w * 32 + c * 8 + lr) * HID + lcs;

                f32x4 acc[4][4] = {};

                for (int k0 = 0; k0 < HID; k0 += BK) {
                    __syncthreads();
                    #pragma unroll
                    for (int c = 0; c < 4; c++)
                        gld_lds16(aptr[c] + k0, &As[(w * 32 + c * 8) * BK]);
                    #pragma unroll
                    for (int c = 0; c < 4; c++)
                        gld_lds16(bptr[c] + k0, &Bs[(w * 32 + c * 8) * BK]);
                    __syncthreads();
                    #pragma unroll
                    for (int ks = 0; ks < 2; ks++) {
                        const int ko = ((ks * 4 + (l >> 4)) ^ (l & 7)) * 8;
                        bf16x8 af[4], bfr[4];
                        #pragma unroll
                        for (int i = 0; i < 4; i++)
                            af[i]  = *(const bf16x8*)&As[(wm * 64 + i * 16 + (l & 15)) * BK + ko];
                        #pragma unroll
                        for (int i = 0; i < 4; i++)
                            bfr[i] = *(const bf16x8*)&Bs[(wn * 64 + i * 16 + (l & 15)) * BK + ko];
                        #pragma unroll
                        for (int mi = 0; mi < 4; mi++)
                            #pragma unroll
                            for (int ni = 0; ni < 4; ni++)
                                acc[mi][ni] = __builtin_amdgcn_mfma_f32_16x16x32_bf16(
                                    af[mi], bfr[ni], acc[mi][ni], 0, 0, 0);
                    }
                }

                const int col = l & 15, quad = l >> 4;
                float bias[4];
                #pragma unroll
                for (int ni = 0; ni < 4; ni++)
                    bias[ni] = b2[e * DIM + nbase + wn * 64 + ni * 16 + col];

                #pragma unroll
                for (int mi = 0; mi < 4; mi++) {
                    #pragma unroll
                    for (int r = 0; r < 4; r++) {
                        const int m = wm * 64 + mi * 16 + quad * 4 + r;
                        if (m < rows) {
                            const int t = sorted_tok[sbase + m];
                            const float tv = top_val[t];
                            #pragma unroll
                            for (int ni = 0; ni < 4; ni++) {
                                const int n = nbase + wn * 64 + ni * 16 + col;
                                float v = acc[mi][ni][r] + bias[ni];
                                yout[(size_t)t * DIM + n] = x[(size_t)t * DIM + n] + v * tv;
                            }
                        }
                    }
                }
            }
        }
    }
    grid_barrier(bar_cnt, bar_gen);

    // ================= phase 5: RMSNorm + exact GeLU ========================
    {
        float* red = (float*)smem;
        for (int t = blockIdx.x; t < T_TOK; t += GRID_BLKS) {
            float* row = yout + (size_t)t * DIM;
            float4 v = *(const float4*)&row[th * 4];
            float ss = v.x * v.x + v.y * v.y + v.z * v.z + v.w * v.w;

            const int lane = th & 63, wave = th >> 6;
            #pragma unroll
            for (int off = 32; off > 0; off >>= 1) ss += __shfl_down(ss, off, 64);
            if (lane == 0) red[wave] = ss;
            __syncthreads();
            float total = red[0] + red[1] + red[2] + red[3];

            float nrm = sqrtf(total);
            float scale = 32.0f / fmaxf(nrm, 1e-12f);   // sqrt(1024) = 32

            float4 g = *(const float4*)&gamma[th * 4];
            float4 o;
            o.x = gelu_exact(v.x * scale * g.x);
            o.y = gelu_exact(v.y * scale * g.y);
            o.z = gelu_exact(v.z * scale * g.z);
            o.w = gelu_exact(v.w * scale * g.w);
            *(float4*)&row[th * 4] = o;
            __syncthreads();   // red reuse across iterations
        }
    }
}

// ---------------------------------------------------------------------------
extern "C" void kernel_launch(void* const* d_in, const int* in_sizes, int n_in,
                              void* d_out, int out_size, void* d_ws, size_t ws_size,
                              hipStream_t stream) {
    const float* x      = (const float*)d_in[0];
    const float* gate_w = (const float*)d_in[1];
    const float* gate_b = (const float*)d_in[2];
    const float* w1     = (const float*)d_in[3];
    const float* b1     = (const float*)d_in[4];
    const float* w2     = (const float*)d_in[5];
    const float* b2     = (const float*)d_in[6];
    const float* gamma  = (const float*)d_in[7];

    float* out  = (float*)d_out;                  // [T*D] y, then [1] loss
    float* loss = out + (size_t)T_TOK * DIM;

    char* ws = (char*)d_ws;
    float* top_val     = (float*)(ws + 0);         // 4096 f
    int*   top_idx     = (int*)  (ws + 16384);     // 4096 i
    int*   sorted_tok  = (int*)  (ws + 32768);     // 4096 i
    int*   bar_cnt     = (int*)  (ws + 49152);     // 1 i (zeroed per launch)
    int*   bar_gen     = (int*)  (ws + 49156);     // 1 i (zeroed per launch)
    int*   tile_e      = (int*)  (ws + 49664);     // 40 i
    int*   tile_s      = (int*)  (ws + 50176);     // 40 i
    int*   tile_rows   = (int*)  (ws + 50688);     // 40 i
    int*   ntiles      = (int*)  (ws + 51200);     // 1 i
    float* partial_imp = (float*)(ws + 65536);     // 1024*8 f = 32 KB
    int*   partial_cnt = (int*)  (ws + 98304);     // 1024*8 i = 32 KB
    u16*   xbf         = (u16*)  (ws + 131072);                      // 8 MiB
    u16*   h_buf       = (u16*)  (ws + 131072 + 8388608);            // 16 MiB
    u16*   w1t         = (u16*)  (ws + 131072 + 8388608 + 16777216);            // 32 MiB
    u16*   w2t         = (u16*)  (ws + 131072 + 8388608 + 16777216 + 33554432); // 32 MiB

    hipMemsetAsync(ws + 49152, 0, 8, stream);      // barrier state

    moe_mega<<<GRID_BLKS, 256, 0, stream>>>(
        x, gate_w, gate_b, w1, b1, w2, b2, gamma,
        w1t, w2t, xbf, h_buf, top_val, top_idx,
        partial_imp, partial_cnt, sorted_tok,
        tile_e, tile_s, tile_rows, ntiles,
        bar_cnt, bar_gen, out, loss);
}

// Round 9
// 379.424 us; speedup vs baseline: 4.8593x; 3.4282x over previous
//
#include <hip/hip_runtime.h>
#include <math.h>

// Problem constants (B=4, N=1024, D=1024, H=2048, E=8)
#define T_TOK 4096
#define DIM   1024
#define HID   2048
#define NE    8
#define TMM   128   // M tile (tokens)
#define BK    64    // K chunk (bf16)
#define GATE_BLOCKS (T_TOK / 4)
// prep ids: [0,4096) w1-transpose, [4096,8192) w2-transpose,
//           [8192,9216) gate, [9216,13312) x->bf16
#define PREP_IDS (8192 + GATE_BLOCKS + T_TOK)

typedef unsigned int  u32;
typedef unsigned short u16;
typedef __attribute__((ext_vector_type(8))) short bf16x8;  // 8 bf16 in 4 VGPRs
typedef __attribute__((ext_vector_type(8))) unsigned short u16x8;
typedef __attribute__((ext_vector_type(4))) float f32x4;

__device__ __forceinline__ float gelu_exact(float v) {
    return 0.5f * v * (1.0f + erff(v * 0.70710678118654752440f));
}

// tanh-form gelu: max abs err vs exact ~1e-3; one v_exp instead of erff poly
__device__ __forceinline__ float gelu_fast(float x) {
    float u = 1.5957691216057308f * (x + 0.044715f * x * x * x); // 2*0.79788456
    float e = __expf(u);                  // exp(2u')
    float t = 1.f - 2.f / (e + 1.f);      // tanh(u')
    return 0.5f * x * (1.f + t);
}

__device__ __forceinline__ u16 f2bf(float v) {
    u32 u = __float_as_uint(v);
    u32 r = (u + 0x7FFFu + ((u >> 16) & 1u)) >> 16;   // RNE
    return (u16)r;
}

// async global->LDS, 16B per lane; lds dest = wave-uniform base + lane*16;
// global source address is PER-LANE (indirection allowed; verified R7/R8).
__device__ __forceinline__ void gld_lds16(const void* g, void* l) {
    __builtin_amdgcn_global_load_lds(
        (const __attribute__((address_space(1))) u32*)g,
        (__attribute__((address_space(3))) u32*)l,
        16, 0, 0);
}

// 64x64 transpose+convert tile: float4 loads, ushort8 (16B) stores.
__device__ __forceinline__ void transpose_body(
    const float* __restrict__ in, u16* __restrict__ out, int R, int C,
    int bx, int by, int bz, float (*tile)[65])
{
    const float* src = in  + (size_t)bz * R * C;
    u16*         dst = out + (size_t)bz * R * C;
    const int c0 = bx * 64, r0 = by * 64;
    const int th = threadIdx.x;

    const int tr  = th >> 4;
    const int tc4 = (th & 15) * 4;
    #pragma unroll
    for (int i = 0; i < 4; i++) {
        const int r = tr + i * 16;
        float4 v = *(const float4*)&src[(size_t)(r0 + r) * C + c0 + tc4];
        tile[r][tc4 + 0] = v.x; tile[r][tc4 + 1] = v.y;
        tile[r][tc4 + 2] = v.z; tile[r][tc4 + 3] = v.w;
    }
    __syncthreads();
    const int cc  = th >> 3;           // 0..31
    const int rr8 = (th & 7) * 8;      // 0..56
    #pragma unroll
    for (int i = 0; i < 2; i++) {
        const int c = cc + i * 32;
        u16x8 o;
        #pragma unroll
        for (int j = 0; j < 8; j++) o[j] = f2bf(tile[rr8 + j][c]);
        *(u16x8*)&dst[(size_t)(c0 + c) * R + r0 + rr8] = o;
    }
}

// ---------------------------------------------------------------------------
// prep_route: transposes + gate + x->bf16, with the LAST-finishing gate
// block inlining the route (plan + scatter) via a device-scope done-counter
// (canonical threadFenceReduction pattern; acq/rel recipe verified by the
// R7 grid barrier).  Kills the separate route + gather launches.
// ---------------------------------------------------------------------------
__global__ __launch_bounds__(256) void prep_route(
    const float* __restrict__ w1, const float* __restrict__ w2,
    u16* __restrict__ w1t, u16* __restrict__ w2t,
    const float* __restrict__ x, const float* __restrict__ gw,
    const float* __restrict__ gb, u16* __restrict__ xbf,
    float* __restrict__ top_val, int* __restrict__ top_idx,
    float* __restrict__ partial_imp, int* __restrict__ partial_cnt,
    int* done, int* __restrict__ sorted_tok,
    int* __restrict__ tile_e, int* __restrict__ tile_s,
    int* __restrict__ tile_rows, int* __restrict__ ntiles,
    float* __restrict__ loss_out)
{
    __shared__ float tile[64][65];
    __shared__ float s_imp[NE];
    __shared__ int   s_cnt[NE];
    __shared__ float rimp[32][NE];
    __shared__ int   rcnt[32][NE];
    __shared__ int   s_off[NE], s_cur[NE];
    __shared__ int   s_flag;

    const int id = blockIdx.x;
    const int th = threadIdx.x;

    if (id < 4096) {
        // w1 [E][D][H] -> w1t [E][H][D]: R=DIM, C=HID, grid (32,16,8)
        transpose_body(w1, w1t, DIM, HID, id & 31, (id >> 5) & 15, id >> 9, tile);
        return;
    }
    if (id < 8192) {
        // w2 [E][H][D] -> w2t [E][D][H]: R=HID, C=DIM, grid (16,32,8)
        const int i2 = id - 4096;
        transpose_body(w2, w2t, HID, DIM, i2 & 15, (i2 >> 4) & 31, i2 >> 9, tile);
        return;
    }
    if (id >= 8192 + GATE_BLOCKS) {
        // ---- x fp32 -> bf16 (token order; ffn1 reads via sorted_tok) ----
        const int row = id - (8192 + GATE_BLOCKS);
        const float* src = x + (size_t)row * DIM;
        u16* dst = xbf + (size_t)row * DIM;
        const int i = th * 4;
        float4 v = *(const float4*)&src[i];
        ushort4 o;
        o.x = f2bf(v.x); o.y = f2bf(v.y); o.z = f2bf(v.z); o.w = f2bf(v.w);
        *(ushort4*)&dst[i] = o;
        return;
    }

    // ---- gate path: block g = id - 8192 in [0, GATE_BLOCKS) ----
    const int g = id - 8192;
    if (th < NE) { s_imp[th] = 0.f; s_cnt[th] = 0; }
    __syncthreads();

    const int wave = th >> 6;
    const int lane = th & 63;
    const int t = g * 4 + wave;

    float acc[NE];
    #pragma unroll
    for (int e = 0; e < NE; e++) acc[e] = 0.f;

    const float* xr = x + (size_t)t * DIM;
    #pragma unroll 4
    for (int k = lane; k < DIM; k += 64) {
        float xv = xr[k];
        const float* gp = gw + (size_t)k * NE;
        float4 g0 = *(const float4*)gp;
        float4 g1 = *(const float4*)(gp + 4);
        acc[0] += xv * g0.x; acc[1] += xv * g0.y;
        acc[2] += xv * g0.z; acc[3] += xv * g0.w;
        acc[4] += xv * g1.x; acc[5] += xv * g1.y;
        acc[6] += xv * g1.z; acc[7] += xv * g1.w;
    }
    #pragma unroll
    for (int e = 0; e < NE; e++) {
        #pragma unroll
        for (int off = 32; off > 0; off >>= 1)
            acc[e] += __shfl_down(acc[e], off, 64);
    }
    if (lane == 0) {
        float l[NE];
        float m = -1e30f;
        #pragma unroll
        for (int e = 0; e < NE; e++) { l[e] = acc[e] + gb[e]; m = fmaxf(m, l[e]); }
        float s = 0.f;
        #pragma unroll
        for (int e = 0; e < NE; e++) { l[e] = expf(l[e] - m); s += l[e]; }
        float inv = 1.f / s;
        int bi = 0; float bv = -1.f;
        #pragma unroll
        for (int e = 0; e < NE; e++) {
            float p = l[e] * inv;
            atomicAdd(&s_imp[e], p);             // LDS atomic
            if (p > bv) { bv = p; bi = e; }      // strict > => first argmax
        }
        top_val[t] = bv;
        top_idx[t] = bi;
        atomicAdd(&s_cnt[bi], 1);
    }
    __syncthreads();
    if (th < NE) {
        partial_imp[g * NE + th] = s_imp[th];
        partial_cnt[g * NE + th] = s_cnt[th];
    }
    __syncthreads();   // all gate stores issued+drained (vmcnt 0) before fence

    // ---- last-arriving gate block performs the route inline ----
    if (th == 0) {
        __threadfence();   // publish this block's partials (agent scope)
        const int old = __hip_atomic_fetch_add(done, 1, __ATOMIC_ACQ_REL,
                                               __HIP_MEMORY_SCOPE_AGENT);
        s_flag = (old == GATE_BLOCKS - 1);   // acquire: L1 invalidated
    }
    __syncthreads();
    if (!s_flag) return;

    // route: reduce 1024 partials -> counts; tile table; scatter; loss
    {
        const int e = th & 7, chunk = th >> 3;   // 32 chunks of 32 gate blocks
        float si = 0.f; int sc = 0;
        #pragma unroll 8
        for (int i = 0; i < GATE_BLOCKS / 32; i++) {
            const int b = chunk * (GATE_BLOCKS / 32) + i;
            si += partial_imp[b * NE + e];
            sc += partial_cnt[b * NE + e];
        }
        rimp[chunk][e] = si;
        rcnt[chunk][e] = sc;
        __syncthreads();
        if (th < NE) {
            float s = 0.f; int c = 0;
            for (int i = 0; i < 32; i++) { s += rimp[i][th]; c += rcnt[i][th]; }
            rimp[0][th] = s;
            rcnt[0][th] = c;
            s_cur[th] = 0;
        }
        __syncthreads();
        if (th == 0) {
            int off = 0, nt = 0;
            for (int ee = 0; ee < NE; ee++) {
                s_off[ee] = off;
                const int c = rcnt[0][ee];
                for (int s = 0; s < c; s += TMM) {
                    tile_e[nt] = ee;
                    tile_s[nt] = off + s;
                    tile_rows[nt] = min(TMM, c - s);
                    nt++;
                }
                off += c;
            }
            *ntiles = nt;   // <= 40

            float mean = 0.f;
            for (int ee = 0; ee < NE; ee++) mean += rimp[0][ee];
            mean *= (1.0f / NE);
            float var = 0.f;
            for (int ee = 0; ee < NE; ee++) { float d = rimp[0][ee] - mean; var += d * d; }
            var *= (1.0f / (NE - 1));
            loss_out[0] = var / (mean * mean + 1e-10f);
        }
        __syncthreads();
        // scatter: 16 rounds x 256 tokens, LDS cursors
        #pragma unroll 4
        for (int r = 0; r < T_TOK / 256; r++) {
            const int tt = r * 256 + th;
            const int te = top_idx[tt];
            const int rank = atomicAdd(&s_cur[te], 1);
            sorted_tok[s_off[te] + rank] = tt;
        }
    }
}

// ---------------------------------------------------------------------------
// FFN1: MFMA 16x16x32, 128x128 tile, 256 thr / 4 waves (2x2, each wave a
// 64x64 quadrant), SINGLE-buffer 32 KB LDS, XOR-swizzled staging.
// A rows gathered through sorted_tok (per-lane global addr; verified R7/R8).
// grid (40 tiles, 16 panels), TILE fastest.  [measured: 64.7 us direct-A]
// ---------------------------------------------------------------------------
__global__ __launch_bounds__(256) void ffn1_mfma(
    const u16* __restrict__ xbf, const u16* __restrict__ w1t,
    const float* __restrict__ b1, const int* __restrict__ sorted_tok,
    const int* __restrict__ tile_e, const int* __restrict__ tile_s,
    const int* __restrict__ tile_rows, const int* __restrict__ ntiles,
    u16* __restrict__ h_buf)
{
    const int tile = blockIdx.x;
    if (tile >= *ntiles) return;
    const int e     = tile_e[tile];
    const int sbase = tile_s[tile];
    const int rows  = tile_rows[tile];
    const int nbase = blockIdx.y * 128;    // over HID, 16 panels

    __shared__ __align__(16) u16 As[128 * BK];   // 16 KB
    __shared__ __align__(16) u16 Bs[128 * BK];   // 16 KB

    const int th = threadIdx.x;
    const int w  = th >> 6;
    const int l  = th & 63;
    const int wm = w >> 1, wn = w & 1;
    const int lr = l >> 3;                  // 0..7 row in staging group
    const int lcs = ((l & 7) ^ lr) * 8;     // swizzled u16 fetch offset

    const u16* aptr[4];
    #pragma unroll
    for (int c = 0; c < 4; c++) {
        int srow = sbase + w * 32 + c * 8 + lr;
        if (srow > T_TOK - 1) srow = T_TOK - 1;
        const int tok = sorted_tok[srow];
        aptr[c] = xbf + (size_t)tok * DIM + lcs;
    }
    const u16* wb = w1t + (size_t)e * HID * DIM + (size_t)nbase * DIM;
    const u16* bptr[4];
    #pragma unroll
    for (int c = 0; c < 4; c++)
        bptr[c] = wb + (size_t)(w * 32 + c * 8 + lr) * DIM + lcs;

    f32x4 acc[4][4] = {};

    for (int k0 = 0; k0 < DIM; k0 += BK) {
        __syncthreads();
        #pragma unroll
        for (int c = 0; c < 4; c++)
            gld_lds16(aptr[c] + k0, &As[(w * 32 + c * 8) * BK]);
        #pragma unroll
        for (int c = 0; c < 4; c++)
            gld_lds16(bptr[c] + k0, &Bs[(w * 32 + c * 8) * BK]);
        __syncthreads();
        #pragma unroll
        for (int ks = 0; ks < 2; ks++) {
            const int ko = ((ks * 4 + (l >> 4)) ^ (l & 7)) * 8;  // swizzled chunk
            bf16x8 af[4], bfr[4];
            #pragma unroll
            for (int i = 0; i < 4; i++)
                af[i]  = *(const bf16x8*)&As[(wm * 64 + i * 16 + (l & 15)) * BK + ko];
            #pragma unroll
            for (int i = 0; i < 4; i++)
                bfr[i] = *(const bf16x8*)&Bs[(wn * 64 + i * 16 + (l & 15)) * BK + ko];
            #pragma unroll
            for (int mi = 0; mi < 4; mi++)
                #pragma unroll
                for (int ni = 0; ni < 4; ni++)
                    acc[mi][ni] = __builtin_amdgcn_mfma_f32_16x16x32_bf16(
                        af[mi], bfr[ni], acc[mi][ni], 0, 0, 0);
        }
    }

    const int col = l & 15, quad = l >> 4;
    #pragma unroll
    for (int ni = 0; ni < 4; ni++) {
        const int n = nbase + wn * 64 + ni * 16 + col;
        const float bias = b1[e * HID + n];
        #pragma unroll
        for (int mi = 0; mi < 4; mi++) {
            #pragma unroll
            for (int r = 0; r < 4; r++) {
                const int m = wm * 64 + mi * 16 + quad * 4 + r;
                if (m < rows) {
                    float v = acc[mi][ni][r] + bias;
                    h_buf[(size_t)(sbase + m) * HID + n] = f2bf(gelu_fast(v));
                }
            }
        }
    }
}

// ---------------------------------------------------------------------------
// FFN2: MFMA 16x16x32, 128x128 tile, 256 thr / 4 waves, SINGLE-buffer 32 KB.
// grid (40 tiles, 8 panels), TILE fastest.
// ---------------------------------------------------------------------------
__global__ __launch_bounds__(256) void ffn2_mfma(
    const u16* __restrict__ h_buf, const u16* __restrict__ w2t,
    const float* __restrict__ b2, const float* __restrict__ x,
    const int* __restrict__ sorted_tok, const float* __restrict__ top_val,
    const int* __restrict__ tile_e, const int* __restrict__ tile_s,
    const int* __restrict__ tile_rows, const int* __restrict__ ntiles,
    float* __restrict__ yout)
{
    const int tile = blockIdx.x;
    if (tile >= *ntiles) return;
    const int e     = tile_e[tile];
    const int sbase = tile_s[tile];
    const int rows  = tile_rows[tile];
    const int nbase = blockIdx.y * 128;    // over DIM, 8 panels

    __shared__ __align__(16) u16 As[128 * BK];
    __shared__ __align__(16) u16 Bs[128 * BK];

    const int th = threadIdx.x;
    const int w  = th >> 6;
    const int l  = th & 63;
    const int wm = w >> 1, wn = w & 1;
    const int lr = l >> 3;
    const int lcs = ((l & 7) ^ lr) * 8;

    const u16* aptr[4];
    #pragma unroll
    for (int c = 0; c < 4; c++) {
        int srow = sbase + w * 32 + c * 8 + lr;
        if (srow > T_TOK - 1) srow = T_TOK - 1;
        aptr[c] = h_buf + (size_t)srow * HID + lcs;
    }
    const u16* wb = w2t + (size_t)e * DIM * HID + (size_t)nbase * HID;
    const u16* bptr[4];
    #pragma unroll
    for (int c = 0; c < 4; c++)
        bptr[c] = wb + (size_t)(w * 32 + c * 8 + lr) * HID + lcs;

    f32x4 acc[4][4] = {};

    for (int k0 = 0; k0 < HID; k0 += BK) {
        __syncthreads();
        #pragma unroll
        for (int c = 0; c < 4; c++)
            gld_lds16(aptr[c] + k0, &As[(w * 32 + c * 8) * BK]);
        #pragma unroll
        for (int c = 0; c < 4; c++)
            gld_lds16(bptr[c] + k0, &Bs[(w * 32 + c * 8) * BK]);
        __syncthreads();
        #pragma unroll
        for (int ks = 0; ks < 2; ks++) {
            const int ko = ((ks * 4 + (l >> 4)) ^ (l & 7)) * 8;
            bf16x8 af[4], bfr[4];
            #pragma unroll
            for (int i = 0; i < 4; i++)
                af[i]  = *(const bf16x8*)&As[(wm * 64 + i * 16 + (l & 15)) * BK + ko];
            #pragma unroll
            for (int i = 0; i < 4; i++)
                bfr[i] = *(const bf16x8*)&Bs[(wn * 64 + i * 16 + (l & 15)) * BK + ko];
            #pragma unroll
            for (int mi = 0; mi < 4; mi++)
                #pragma unroll
                for (int ni = 0; ni < 4; ni++)
                    acc[mi][ni] = __builtin_amdgcn_mfma_f32_16x16x32_bf16(
                        af[mi], bfr[ni], acc[mi][ni], 0, 0, 0);
        }
    }

    const int col = l & 15, quad = l >> 4;
    float bias[4];
    #pragma unroll
    for (int ni = 0; ni < 4; ni++)
        bias[ni] = b2[e * DIM + nbase + wn * 64 + ni * 16 + col];

    #pragma unroll
    for (int mi = 0; mi < 4; mi++) {
        #pragma unroll
        for (int r = 0; r < 4; r++) {
            const int m = wm * 64 + mi * 16 + quad * 4 + r;
            if (m < rows) {
                const int t = sorted_tok[sbase + m];
                const float tv = top_val[t];
                #pragma unroll
                for (int ni = 0; ni < 4; ni++) {
                    const int n = nbase + wn * 64 + ni * 16 + col;
                    float v = acc[mi][ni][r] + bias[ni];
                    yout[(size_t)t * DIM + n] = x[(size_t)t * DIM + n] + v * tv;
                }
            }
        }
    }
}

// ---------------------------------------------------------------------------
// RMSNorm (F.normalize * gamma * sqrt(D)) + exact GeLU, in place.
// ---------------------------------------------------------------------------
__global__ __launch_bounds__(256) void norm_kernel(float* __restrict__ y,
                                                   const float* __restrict__ gamma)
{
    const int t = blockIdx.x;
    float* row = y + (size_t)t * DIM;
    const int th = threadIdx.x;
    float4 v = *(const float4*)&row[th * 4];
    float ss = v.x * v.x + v.y * v.y + v.z * v.z + v.w * v.w;

    const int lane = th & 63, wave = th >> 6;
    #pragma unroll
    for (int off = 32; off > 0; off >>= 1) ss += __shfl_down(ss, off, 64);
    __shared__ float red[4];
    if (lane == 0) red[wave] = ss;
    __syncthreads();
    float total = red[0] + red[1] + red[2] + red[3];

    float nrm = sqrtf(total);
    float scale = 32.0f / fmaxf(nrm, 1e-12f);   // sqrt(1024) = 32

    float4 g = *(const float4*)&gamma[th * 4];
    float4 o;
    o.x = gelu_exact(v.x * scale * g.x);
    o.y = gelu_exact(v.y * scale * g.y);
    o.z = gelu_exact(v.z * scale * g.z);
    o.w = gelu_exact(v.w * scale * g.w);
    *(float4*)&row[th * 4] = o;
}

// ---------------------------------------------------------------------------
extern "C" void kernel_launch(void* const* d_in, const int* in_sizes, int n_in,
                              void* d_out, int out_size, void* d_ws, size_t ws_size,
                              hipStream_t stream) {
    const float* x      = (const float*)d_in[0];
    const float* gate_w = (const float*)d_in[1];
    const float* gate_b = (const float*)d_in[2];
    const float* w1     = (const float*)d_in[3];
    const float* b1     = (const float*)d_in[4];
    const float* w2     = (const float*)d_in[5];
    const float* b2     = (const float*)d_in[6];
    const float* gamma  = (const float*)d_in[7];

    float* out  = (float*)d_out;                  // [T*D] y, then [1] loss
    float* loss = out + (size_t)T_TOK * DIM;

    char* ws = (char*)d_ws;
    float* top_val     = (float*)(ws + 0);         // 4096 f
    int*   top_idx     = (int*)  (ws + 16384);     // 4096 i
    int*   sorted_tok  = (int*)  (ws + 32768);     // 4096 i
    int*   done        = (int*)  (ws + 49152);     // 1 i (zeroed per launch)
    int*   tile_e      = (int*)  (ws + 49664);     // 40 i
    int*   tile_s      = (int*)  (ws + 50176);     // 40 i
    int*   tile_rows   = (int*)  (ws + 50688);     // 40 i
    int*   ntiles      = (int*)  (ws + 51200);     // 1 i
    float* partial_imp = (float*)(ws + 65536);     // 1024*8 f = 32 KB
    int*   partial_cnt = (int*)  (ws + 98304);     // 1024*8 i = 32 KB
    u16*   xbf         = (u16*)  (ws + 131072);                      // 8 MiB
    u16*   h_buf       = (u16*)  (ws + 131072 + 8388608);            // 16 MiB
    u16*   w1t         = (u16*)  (ws + 131072 + 8388608 + 16777216);            // 32 MiB
    u16*   w2t         = (u16*)  (ws + 131072 + 8388608 + 16777216 + 33554432); // 32 MiB

    hipMemsetAsync(ws + 49152, 0, 4, stream);      // done counter

    // transposes + gate + x->bf16 + inline route (last gate block)
    prep_route<<<PREP_IDS, 256, 0, stream>>>(
        w1, w2, w1t, w2t, x, gate_w, gate_b, xbf, top_val, top_idx,
        partial_imp, partial_cnt, done, sorted_tok,
        tile_e, tile_s, tile_rows, ntiles, loss);

    // TILE-fastest grids (measured best)
    ffn1_mfma<<<dim3(40, HID / 128), 256, 0, stream>>>(
        xbf, w1t, b1, sorted_tok, tile_e, tile_s, tile_rows, ntiles, h_buf);
    ffn2_mfma<<<dim3(40, DIM / 128), 256, 0, stream>>>(
        h_buf, w2t, b2, x, sorted_tok, top_val, tile_e, tile_s, tile_rows,
        ntiles, out);
    norm_kernel<<<T_TOK, 256, 0, stream>>>(out, gamma);
}

// Round 10
// 301.712 us; speedup vs baseline: 6.1110x; 1.2576x over previous
//
#include <hip/hip_runtime.h>
#include <math.h>

// Problem constants (B=4, N=1024, D=1024, H=2048, E=8)
#define T_TOK 4096
#define DIM   1024
#define HID   2048
#define NE    8
#define TMM   128   // M tile (tokens)
#define BK    64    // K chunk (bf16)
#define GATE_BLOCKS (T_TOK / 4)

typedef unsigned int  u32;
typedef unsigned short u16;
typedef __attribute__((ext_vector_type(8))) short bf16x8;  // 8 bf16 in 4 VGPRs
typedef __attribute__((ext_vector_type(8))) unsigned short u16x8;
typedef __attribute__((ext_vector_type(4))) float f32x4;

__device__ __forceinline__ float gelu_exact(float v) {
    return 0.5f * v * (1.0f + erff(v * 0.70710678118654752440f));
}

// tanh-form gelu: max abs err vs exact ~1e-3; one v_exp instead of erff poly
__device__ __forceinline__ float gelu_fast(float x) {
    float u = 1.5957691216057308f * (x + 0.044715f * x * x * x); // 2*0.79788456
    float e = __expf(u);                  // exp(2u')
    float t = 1.f - 2.f / (e + 1.f);      // tanh(u')
    return 0.5f * x * (1.f + t);
}

__device__ __forceinline__ u16 f2bf(float v) {
    u32 u = __float_as_uint(v);
    u32 r = (u + 0x7FFFu + ((u >> 16) & 1u)) >> 16;   // RNE
    return (u16)r;
}

// async global->LDS, 16B per lane; lds dest = wave-uniform base + lane*16
__device__ __forceinline__ void gld_lds16(const void* g, void* l) {
    __builtin_amdgcn_global_load_lds(
        (const __attribute__((address_space(1))) u32*)g,
        (__attribute__((address_space(3))) u32*)l,
        16, 0, 0);
}

// ---------------------------------------------------------------------------
// Fused prep: blocks [0,4096) transpose w1, [4096,8192) transpose w2,
// [8192,9216) gate.  NO device-scope fences (R9 lesson: per-block agent
// fences thrashed L2 writeback, prep 72->143us).  [measured: ~71-73us]
// ---------------------------------------------------------------------------
__device__ __forceinline__ void transpose_body(
    const float* __restrict__ in, u16* __restrict__ out, int R, int C,
    int bx, int by, int bz, float (*tile)[65])
{
    const float* src = in  + (size_t)bz * R * C;
    u16*         dst = out + (size_t)bz * R * C;
    const int c0 = bx * 64, r0 = by * 64;
    const int th = threadIdx.x;

    const int tr  = th >> 4;
    const int tc4 = (th & 15) * 4;
    #pragma unroll
    for (int i = 0; i < 4; i++) {
        const int r = tr + i * 16;
        float4 v = *(const float4*)&src[(size_t)(r0 + r) * C + c0 + tc4];
        tile[r][tc4 + 0] = v.x; tile[r][tc4 + 1] = v.y;
        tile[r][tc4 + 2] = v.z; tile[r][tc4 + 3] = v.w;
    }
    __syncthreads();
    const int cc  = th >> 3;           // 0..31
    const int rr8 = (th & 7) * 8;      // 0..56
    #pragma unroll
    for (int i = 0; i < 2; i++) {
        const int c = cc + i * 32;
        u16x8 o;
        #pragma unroll
        for (int j = 0; j < 8; j++) o[j] = f2bf(tile[rr8 + j][c]);
        *(u16x8*)&dst[(size_t)(c0 + c) * R + r0 + rr8] = o;
    }
}

__global__ __launch_bounds__(256) void prep_kernel(
    const float* __restrict__ w1, const float* __restrict__ w2,
    u16* __restrict__ w1t, u16* __restrict__ w2t,
    const float* __restrict__ x, const float* __restrict__ gw,
    const float* __restrict__ gb, float* __restrict__ top_val,
    int* __restrict__ top_idx, float* __restrict__ partial_imp,
    int* __restrict__ partial_cnt)
{
    __shared__ float tile[64][65];
    __shared__ float s_imp[NE];
    __shared__ int   s_cnt[NE];

    const int id = blockIdx.x;
    if (id < 4096) {
        // w1 [E][D][H] -> w1t [E][H][D]: R=DIM, C=HID, grid (32,16,8)
        transpose_body(w1, w1t, DIM, HID, id & 31, (id >> 5) & 15, id >> 9, tile);
        return;
    }
    if (id < 8192) {
        // w2 [E][H][D] -> w2t [E][D][H]: R=HID, C=DIM, grid (16,32,8)
        const int i2 = id - 4096;
        transpose_body(w2, w2t, HID, DIM, i2 & 15, (i2 >> 4) & 31, i2 >> 9, tile);
        return;
    }

    // ---- gate path: block g = id - 8192 in [0, GATE_BLOCKS) ----
    const int g = id - 8192;
    const int th = threadIdx.x;
    if (th < NE) { s_imp[th] = 0.f; s_cnt[th] = 0; }
    __syncthreads();

    const int wave = th >> 6;
    const int lane = th & 63;
    const int t = g * 4 + wave;

    float acc[NE];
    #pragma unroll
    for (int e = 0; e < NE; e++) acc[e] = 0.f;

    const float* xr = x + (size_t)t * DIM;
    #pragma unroll 4
    for (int k = lane; k < DIM; k += 64) {
        float xv = xr[k];
        const float* gp = gw + (size_t)k * NE;
        float4 g0 = *(const float4*)gp;
        float4 g1 = *(const float4*)(gp + 4);
        acc[0] += xv * g0.x; acc[1] += xv * g0.y;
        acc[2] += xv * g0.z; acc[3] += xv * g0.w;
        acc[4] += xv * g1.x; acc[5] += xv * g1.y;
        acc[6] += xv * g1.z; acc[7] += xv * g1.w;
    }
    #pragma unroll
    for (int e = 0; e < NE; e++) {
        #pragma unroll
        for (int off = 32; off > 0; off >>= 1)
            acc[e] += __shfl_down(acc[e], off, 64);
    }
    if (lane == 0) {
        float l[NE];
        float m = -1e30f;
        #pragma unroll
        for (int e = 0; e < NE; e++) { l[e] = acc[e] + gb[e]; m = fmaxf(m, l[e]); }
        float s = 0.f;
        #pragma unroll
        for (int e = 0; e < NE; e++) { l[e] = expf(l[e] - m); s += l[e]; }
        float inv = 1.f / s;
        int bi = 0; float bv = -1.f;
        #pragma unroll
        for (int e = 0; e < NE; e++) {
            float p = l[e] * inv;
            atomicAdd(&s_imp[e], p);             // LDS atomic
            if (p > bv) { bv = p; bi = e; }      // strict > => first argmax
        }
        top_val[t] = bv;
        top_idx[t] = bi;
        atomicAdd(&s_cnt[bi], 1);
    }
    __syncthreads();
    if (th < NE) {
        partial_imp[g * NE + th] = s_imp[th];
        partial_cnt[g * NE + th] = s_cnt[th];
    }
}

// ---------------------------------------------------------------------------
// Route (1 block, 256 thr): plan + scatter fused, LDS cursors (no memset).
// [verified R5]
// ---------------------------------------------------------------------------
__global__ __launch_bounds__(256) void route_kernel(
    const float* __restrict__ partial_imp, const int* __restrict__ partial_cnt,
    const int* __restrict__ top_idx,
    int* __restrict__ sorted_tok,
    int* __restrict__ tile_e, int* __restrict__ tile_s,
    int* __restrict__ tile_rows, int* __restrict__ ntiles,
    float* __restrict__ loss_out)
{
    __shared__ float rimp[32][NE];
    __shared__ int   rcnt[32][NE];
    __shared__ int   s_off[NE];
    __shared__ int   s_cur[NE];
    const int th = threadIdx.x;
    const int e = th & 7, chunk = th >> 3;   // 32 chunks of 32 blocks
    float si = 0.f; int sc = 0;
    #pragma unroll 8
    for (int i = 0; i < GATE_BLOCKS / 32; i++) {
        const int b = chunk * (GATE_BLOCKS / 32) + i;
        si += partial_imp[b * NE + e];
        sc += partial_cnt[b * NE + e];
    }
    rimp[chunk][e] = si;
    rcnt[chunk][e] = sc;
    __syncthreads();
    if (th < NE) {
        float s = 0.f; int c = 0;
        for (int i = 0; i < 32; i++) { s += rimp[i][th]; c += rcnt[i][th]; }
        rimp[0][th] = s;
        rcnt[0][th] = c;
        s_cur[th] = 0;
    }
    __syncthreads();
    if (th == 0) {
        int off = 0, nt = 0;
        for (int ee = 0; ee < NE; ee++) {
            s_off[ee] = off;
            const int c = rcnt[0][ee];
            for (int s = 0; s < c; s += TMM) {
                tile_e[nt] = ee;
                tile_s[nt] = off + s;
                tile_rows[nt] = min(TMM, c - s);
                nt++;
            }
            off += c;
        }
        *ntiles = nt;   // <= 40

        float mean = 0.f;
        for (int ee = 0; ee < NE; ee++) mean += rimp[0][ee];
        mean *= (1.0f / NE);
        float var = 0.f;
        for (int ee = 0; ee < NE; ee++) { float d = rimp[0][ee] - mean; var += d * d; }
        var *= (1.0f / (NE - 1));
        loss_out[0] = var / (mean * mean + 1e-10f);
    }
    __syncthreads();
    // scatter: 16 rounds x 256 tokens, LDS cursors
    #pragma unroll 4
    for (int r = 0; r < T_TOK / 256; r++) {
        const int t  = r * 256 + th;
        const int te = top_idx[t];
        const int rank = atomicAdd(&s_cur[te], 1);
        sorted_tok[s_off[te] + rank] = t;
    }
}

// ---------------------------------------------------------------------------
// Gather x rows into sorted order, fp32 -> bf16. One block per sorted row.
// ---------------------------------------------------------------------------
__global__ __launch_bounds__(256) void gather_x_kernel(
    const float* __restrict__ x, const int* __restrict__ sorted_tok,
    u16* __restrict__ xs)
{
    const int s = blockIdx.x;
    const int tok = sorted_tok[s];
    const float* src = x + (size_t)tok * DIM;
    u16* dst = xs + (size_t)s * DIM;
    const int i = threadIdx.x * 4;
    float4 v = *(const float4*)&src[i];
    ushort4 o;
    o.x = f2bf(v.x); o.y = f2bf(v.y); o.z = f2bf(v.z); o.w = f2bf(v.w);
    *(ushort4*)&dst[i] = o;
}

// ---------------------------------------------------------------------------
// FFN1: MFMA 16x16x32, 128x256 tile, 512 thr / 8 waves (2M x 4N, each wave
// a 64x64 quadrant), SINGLE-buffer 48 KB LDS, XOR-swizzled staging.
// grid (40 tiles, 8 panels), TILE FASTEST (R1-vs-R4 A/B: tile-fastest wins
// by ~25% -- XCD-local A-tiles, B panels broadcast via L3).
// ---------------------------------------------------------------------------
__global__ __launch_bounds__(512) void ffn1_mfma(
    const u16* __restrict__ xs, const u16* __restrict__ w1t,
    const float* __restrict__ b1,
    const int* __restrict__ tile_e, const int* __restrict__ tile_s,
    const int* __restrict__ tile_rows, const int* __restrict__ ntiles,
    u16* __restrict__ h_buf)
{
    const int tile = blockIdx.x;
    if (tile >= *ntiles) return;
    const int e     = tile_e[tile];
    const int sbase = tile_s[tile];
    const int rows  = tile_rows[tile];
    const int nbase = blockIdx.y * 256;    // over HID, 8 panels

    __shared__ __align__(16) u16 As[128 * BK];   // 16 KB
    __shared__ __align__(16) u16 Bs[256 * BK];   // 32 KB

    const int th = threadIdx.x;
    const int w  = th >> 6;               // 0..7
    const int l  = th & 63;
    const int wm = w >> 2, wn = w & 3;    // 2M x 4N wave grid
    const int lr = l >> 3;                // 0..7 row in staging group
    const int lcs = ((l & 7) ^ lr) * 8;   // swizzled u16 fetch offset

    // A staging: 2 rounds; round c covers rows c*64 + w*8 + lr
    const u16* aptr[2];
    #pragma unroll
    for (int c = 0; c < 2; c++) {
        int srow = sbase + c * 64 + w * 8 + lr;
        if (srow > T_TOK - 1) srow = T_TOK - 1;
        aptr[c] = xs + (size_t)srow * DIM + lcs;
    }
    // B staging: 4 rounds over 256 W1t rows
    const u16* wb = w1t + (size_t)e * HID * DIM + (size_t)nbase * DIM;
    const u16* bptr[4];
    #pragma unroll
    for (int c = 0; c < 4; c++)
        bptr[c] = wb + (size_t)(c * 64 + w * 8 + lr) * DIM + lcs;

    f32x4 acc[4][4] = {};

    for (int k0 = 0; k0 < DIM; k0 += BK) {
        __syncthreads();
        #pragma unroll
        for (int c = 0; c < 2; c++)
            gld_lds16(aptr[c] + k0, &As[(c * 64 + w * 8) * BK]);
        #pragma unroll
        for (int c = 0; c < 4; c++)
            gld_lds16(bptr[c] + k0, &Bs[(c * 64 + w * 8) * BK]);
        __syncthreads();
        #pragma unroll
        for (int ks = 0; ks < 2; ks++) {
            const int ko = ((ks * 4 + (l >> 4)) ^ (l & 7)) * 8;  // swizzled chunk
            bf16x8 af[4], bfr[4];
            #pragma unroll
            for (int i = 0; i < 4; i++)
                af[i]  = *(const bf16x8*)&As[(wm * 64 + i * 16 + (l & 15)) * BK + ko];
            #pragma unroll
            for (int i = 0; i < 4; i++)
                bfr[i] = *(const bf16x8*)&Bs[(wn * 64 + i * 16 + (l & 15)) * BK + ko];
            #pragma unroll
            for (int mi = 0; mi < 4; mi++)
                #pragma unroll
                for (int ni = 0; ni < 4; ni++)
                    acc[mi][ni] = __builtin_amdgcn_mfma_f32_16x16x32_bf16(
                        af[mi], bfr[ni], acc[mi][ni], 0, 0, 0);
        }
    }

    const int col = l & 15, quad = l >> 4;
    #pragma unroll
    for (int ni = 0; ni < 4; ni++) {
        const int n = nbase + wn * 64 + ni * 16 + col;
        const float bias = b1[e * HID + n];
        #pragma unroll
        for (int mi = 0; mi < 4; mi++) {
            #pragma unroll
            for (int r = 0; r < 4; r++) {
                const int m = wm * 64 + mi * 16 + quad * 4 + r;
                if (m < rows) {
                    float v = acc[mi][ni][r] + bias;
                    h_buf[(size_t)(sbase + m) * HID + n] = f2bf(gelu_fast(v));
                }
            }
        }
    }
}

// ---------------------------------------------------------------------------
// FFN2: MFMA 16x16x32, 128x128 tile, 256 thr / 4 waves, SINGLE-buffer 32 KB.
// grid (40 tiles, 8 panels), TILE FASTEST (h_buf tiles XCD-local from ffn1).
// [measured R1: <=64.6us at this config]
// ---------------------------------------------------------------------------
__global__ __launch_bounds__(256) void ffn2_mfma(
    const u16* __restrict__ h_buf, const u16* __restrict__ w2t,
    const float* __restrict__ b2, const float* __restrict__ x,
    const int* __restrict__ sorted_tok, const float* __restrict__ top_val,
    const int* __restrict__ tile_e, const int* __restrict__ tile_s,
    const int* __restrict__ tile_rows, const int* __restrict__ ntiles,
    float* __restrict__ yout)
{
    const int tile = blockIdx.x;
    if (tile >= *ntiles) return;
    const int e     = tile_e[tile];
    const int sbase = tile_s[tile];
    const int rows  = tile_rows[tile];
    const int nbase = blockIdx.y * 128;    // over DIM, 8 panels

    __shared__ __align__(16) u16 As[128 * BK];
    __shared__ __align__(16) u16 Bs[128 * BK];

    const int th = threadIdx.x;
    const int w  = th >> 6;
    const int l  = th & 63;
    const int wm = w >> 1, wn = w & 1;
    const int lr = l >> 3;
    const int lcs = ((l & 7) ^ lr) * 8;

    const u16* aptr[4];
    #pragma unroll
    for (int c = 0; c < 4; c++) {
        int srow = sbase + w * 32 + c * 8 + lr;
        if (srow > T_TOK - 1) srow = T_TOK - 1;
        aptr[c] = h_buf + (size_t)srow * HID + lcs;
    }
    const u16* wb = w2t + (size_t)e * DIM * HID + (size_t)nbase * HID;
    const u16* bptr[4];
    #pragma unroll
    for (int c = 0; c < 4; c++)
        bptr[c] = wb + (size_t)(w * 32 + c * 8 + lr) * HID + lcs;

    f32x4 acc[4][4] = {};

    for (int k0 = 0; k0 < HID; k0 += BK) {
        __syncthreads();
        #pragma unroll
        for (int c = 0; c < 4; c++)
            gld_lds16(aptr[c] + k0, &As[(w * 32 + c * 8) * BK]);
        #pragma unroll
        for (int c = 0; c < 4; c++)
            gld_lds16(bptr[c] + k0, &Bs[(w * 32 + c * 8) * BK]);
        __syncthreads();
        #pragma unroll
        for (int ks = 0; ks < 2; ks++) {
            const int ko = ((ks * 4 + (l >> 4)) ^ (l & 7)) * 8;
            bf16x8 af[4], bfr[4];
            #pragma unroll
            for (int i = 0; i < 4; i++)
                af[i]  = *(const bf16x8*)&As[(wm * 64 + i * 16 + (l & 15)) * BK + ko];
            #pragma unroll
            for (int i = 0; i < 4; i++)
                bfr[i] = *(const bf16x8*)&Bs[(wn * 64 + i * 16 + (l & 15)) * BK + ko];
            #pragma unroll
            for (int mi = 0; mi < 4; mi++)
                #pragma unroll
                for (int ni = 0; ni < 4; ni++)
                    acc[mi][ni] = __builtin_amdgcn_mfma_f32_16x16x32_bf16(
                        af[mi], bfr[ni], acc[mi][ni], 0, 0, 0);
        }
    }

    const int col = l & 15, quad = l >> 4;
    float bias[4];
    #pragma unroll
    for (int ni = 0; ni < 4; ni++)
        bias[ni] = b2[e * DIM + nbase + wn * 64 + ni * 16 + col];

    #pragma unroll
    for (int mi = 0; mi < 4; mi++) {
        #pragma unroll
        for (int r = 0; r < 4; r++) {
            const int m = wm * 64 + mi * 16 + quad * 4 + r;
            if (m < rows) {
                const int t = sorted_tok[sbase + m];
                const float tv = top_val[t];
                #pragma unroll
                for (int ni = 0; ni < 4; ni++) {
                    const int n = nbase + wn * 64 + ni * 16 + col;
                    float v = acc[mi][ni][r] + bias[ni];
                    yout[(size_t)t * DIM + n] = x[(size_t)t * DIM + n] + v * tv;
                }
            }
        }
    }
}

// ---------------------------------------------------------------------------
// RMSNorm (F.normalize * gamma * sqrt(D)) + exact GeLU, in place.
// ---------------------------------------------------------------------------
__global__ __launch_bounds__(256) void norm_kernel(float* __restrict__ y,
                                                   const float* __restrict__ gamma)
{
    const int t = blockIdx.x;
    float* row = y + (size_t)t * DIM;
    const int th = threadIdx.x;
    float4 v = *(const float4*)&row[th * 4];
    float ss = v.x * v.x + v.y * v.y + v.z * v.z + v.w * v.w;

    const int lane = th & 63, wave = th >> 6;
    #pragma unroll
    for (int off = 32; off > 0; off >>= 1) ss += __shfl_down(ss, off, 64);
    __shared__ float red[4];
    if (lane == 0) red[wave] = ss;
    __syncthreads();
    float total = red[0] + red[1] + red[2] + red[3];

    float nrm = sqrtf(total);
    float scale = 32.0f / fmaxf(nrm, 1e-12f);   // sqrt(1024) = 32

    float4 g = *(const float4*)&gamma[th * 4];
    float4 o;
    o.x = gelu_exact(v.x * scale * g.x);
    o.y = gelu_exact(v.y * scale * g.y);
    o.z = gelu_exact(v.z * scale * g.z);
    o.w = gelu_exact(v.w * scale * g.w);
    *(float4*)&row[th * 4] = o;
}

// ---------------------------------------------------------------------------
extern "C" void kernel_launch(void* const* d_in, const int* in_sizes, int n_in,
                              void* d_out, int out_size, void* d_ws, size_t ws_size,
                              hipStream_t stream) {
    const float* x      = (const float*)d_in[0];
    const float* gate_w = (const float*)d_in[1];
    const float* gate_b = (const float*)d_in[2];
    const float* w1     = (const float*)d_in[3];
    const float* b1     = (const float*)d_in[4];
    const float* w2     = (const float*)d_in[5];
    const float* b2     = (const float*)d_in[6];
    const float* gamma  = (const float*)d_in[7];

    float* out  = (float*)d_out;                  // [T*D] y, then [1] loss
    float* loss = out + (size_t)T_TOK * DIM;

    char* ws = (char*)d_ws;
    float* top_val     = (float*)(ws + 0);         // 4096 f
    int*   top_idx     = (int*)  (ws + 16384);     // 4096 i
    int*   sorted_tok  = (int*)  (ws + 32768);     // 4096 i
    int*   tile_e      = (int*)  (ws + 49664);     // 40 i
    int*   tile_s      = (int*)  (ws + 50176);     // 40 i
    int*   tile_rows   = (int*)  (ws + 50688);     // 40 i
    int*   ntiles      = (int*)  (ws + 51200);     // 1 i
    float* partial_imp = (float*)(ws + 65536);     // 1024*8 f = 32 KB
    int*   partial_cnt = (int*)  (ws + 98304);     // 1024*8 i = 32 KB
    u16*   x_sorted    = (u16*)  (ws + 131072);                      // 8 MiB
    u16*   h_buf       = (u16*)  (ws + 131072 + 8388608);            // 16 MiB
    u16*   w1t         = (u16*)  (ws + 131072 + 8388608 + 16777216);            // 32 MiB
    u16*   w2t         = (u16*)  (ws + 131072 + 8388608 + 16777216 + 33554432); // 32 MiB

    // fused transposes + gate (8192 + 1024 blocks, all independent)
    prep_kernel<<<8192 + GATE_BLOCKS, 256, 0, stream>>>(
        w1, w2, w1t, w2t, x, gate_w, gate_b, top_val, top_idx,
        partial_imp, partial_cnt);
    // plan + scatter fused, single block (LDS cursors -> no memset)
    route_kernel<<<1, 256, 0, stream>>>(partial_imp, partial_cnt, top_idx,
                                        sorted_tok, tile_e, tile_s, tile_rows,
                                        ntiles, loss);
    gather_x_kernel<<<T_TOK, 256, 0, stream>>>(x, sorted_tok, x_sorted);

    // TILE-fastest grids (R1-vs-R4 A/B: tile-fastest beats panel-fastest)
    ffn1_mfma<<<dim3(40, HID / 256), 512, 0, stream>>>(
        x_sorted, w1t, b1, tile_e, tile_s, tile_rows, ntiles, h_buf);
    ffn2_mfma<<<dim3(40, DIM / 128), 256, 0, stream>>>(
        h_buf, w2t, b2, x, sorted_tok, top_val, tile_e, tile_s, tile_rows,
        ntiles, out);
    norm_kernel<<<T_TOK, 256, 0, stream>>>(out, gamma);
}

// Round 11
// 296.234 us; speedup vs baseline: 6.2240x; 1.0185x over previous
//
#include <hip/hip_runtime.h>
#include <math.h>

// Problem constants (B=4, N=1024, D=1024, H=2048, E=8)
#define T_TOK 4096
#define DIM   1024
#define HID   2048
#define NE    8
#define TMM   128   // M tile (tokens)
#define BK    64    // K chunk (bf16)
#define GATE_BLOCKS (T_TOK / 4)
// prep ids: [0,2048) w1-transpose(64x128), [2048,4096) w2-transpose(64x128),
//           [4096,5120) gate(+inline x->bf16)
#define PREP_IDS (4096 + GATE_BLOCKS)

typedef unsigned int  u32;
typedef unsigned short u16;
typedef __attribute__((ext_vector_type(8))) short bf16x8;  // 8 bf16 in 4 VGPRs
typedef __attribute__((ext_vector_type(8))) unsigned short u16x8;
typedef __attribute__((ext_vector_type(4))) float f32x4;

__device__ __forceinline__ float gelu_exact(float v) {
    return 0.5f * v * (1.0f + erff(v * 0.70710678118654752440f));
}

// tanh-form gelu: max abs err vs exact ~1e-3; one v_exp instead of erff poly
__device__ __forceinline__ float gelu_fast(float x) {
    float u = 1.5957691216057308f * (x + 0.044715f * x * x * x); // 2*0.79788456
    float e = __expf(u);                  // exp(2u')
    float t = 1.f - 2.f / (e + 1.f);      // tanh(u')
    return 0.5f * x * (1.f + t);
}

__device__ __forceinline__ u16 f2bf(float v) {
    u32 u = __float_as_uint(v);
    u32 r = (u + 0x7FFFu + ((u >> 16) & 1u)) >> 16;   // RNE
    return (u16)r;
}

// async global->LDS, 16B per lane; lds dest = wave-uniform base + lane*16;
// global source address is PER-LANE (indirection allowed; verified R7-R9).
__device__ __forceinline__ void gld_lds16(const void* g, void* l) {
    __builtin_amdgcn_global_load_lds(
        (const __attribute__((address_space(1))) u32*)g,
        (__attribute__((address_space(3))) u32*)l,
        16, 0, 0);
}

// ---------------------------------------------------------------------------
// 64x128 transpose+convert per block, register-staged: all 8 float4 loads
// issued up front (2x MLP vs 64x64 version -- prep was latency-bound at 58%
// occupancy, 8.5% VALU), then two sequential 64x64 LDS half-passes.
// LDS stays 16.6 KB (9 blocks/CU ceiling unchanged).  No device-scope
// fences anywhere (R9 lesson).
// ---------------------------------------------------------------------------
__device__ __forceinline__ void transpose_body2(
    const float* __restrict__ in, u16* __restrict__ out, int R, int C,
    int bx, int by, int bz, float (*tile)[65])
{
    const float* src = in  + (size_t)bz * R * C;
    u16*         dst = out + (size_t)bz * R * C;
    const int c0 = bx * 128, r0 = by * 64;
    const int th = threadIdx.x;

    const int tr  = th >> 4;
    const int tc4 = (th & 15) * 4;

    // stage BOTH 64x64 halves into registers (8 independent loads in flight)
    float4 v[2][4];
    #pragma unroll
    for (int h = 0; h < 2; h++)
        #pragma unroll
        for (int i = 0; i < 4; i++)
            v[h][i] = *(const float4*)&src[(size_t)(r0 + tr + i * 16) * C +
                                           c0 + h * 64 + tc4];

    #pragma unroll
    for (int h = 0; h < 2; h++) {
        if (h) __syncthreads();      // all reads of half 0 done before overwrite
        #pragma unroll
        for (int i = 0; i < 4; i++) {
            const int r = tr + i * 16;
            tile[r][tc4 + 0] = v[h][i].x; tile[r][tc4 + 1] = v[h][i].y;
            tile[r][tc4 + 2] = v[h][i].z; tile[r][tc4 + 3] = v[h][i].w;
        }
        __syncthreads();
        const int cc  = th >> 3;           // 0..31
        const int rr8 = (th & 7) * 8;      // 0..56
        #pragma unroll
        for (int i = 0; i < 2; i++) {
            const int c = cc + i * 32;
            u16x8 o;
            #pragma unroll
            for (int j = 0; j < 8; j++) o[j] = f2bf(tile[rr8 + j][c]);
            *(u16x8*)&dst[(size_t)(c0 + h * 64 + c) * R + r0 + rr8] = o;
        }
    }
}

__global__ __launch_bounds__(256) void prep_kernel(
    const float* __restrict__ w1, const float* __restrict__ w2,
    u16* __restrict__ w1t, u16* __restrict__ w2t,
    const float* __restrict__ x, const float* __restrict__ gw,
    const float* __restrict__ gb, u16* __restrict__ xbf,
    float* __restrict__ top_val, int* __restrict__ top_idx,
    float* __restrict__ partial_imp, int* __restrict__ partial_cnt)
{
    __shared__ float tile[64][65];
    __shared__ float s_imp[NE];
    __shared__ int   s_cnt[NE];

    const int id = blockIdx.x;
    if (id < 2048) {
        // w1 [E][D][H] -> w1t [E][H][D]: R=DIM, C=HID, grid (16,16,8)
        transpose_body2(w1, w1t, DIM, HID, id & 15, (id >> 4) & 15, id >> 8, tile);
        return;
    }
    if (id < 4096) {
        // w2 [E][H][D] -> w2t [E][D][H]: R=HID, C=DIM, grid (8,32,8)
        const int i2 = id - 2048;
        transpose_body2(w2, w2t, HID, DIM, i2 & 7, (i2 >> 3) & 31, i2 >> 8, tile);
        return;
    }

    // ---- gate path: block g = id - 4096; also emits x->bf16 inline ----
    const int g = id - 4096;
    const int th = threadIdx.x;
    if (th < NE) { s_imp[th] = 0.f; s_cnt[th] = 0; }
    __syncthreads();

    const int wave = th >> 6;
    const int lane = th & 63;
    const int t = g * 4 + wave;

    float acc[NE];
    #pragma unroll
    for (int e = 0; e < NE; e++) acc[e] = 0.f;

    const float* xr = x + (size_t)t * DIM;
    u16* xb = xbf + (size_t)t * DIM;
    #pragma unroll 4
    for (int k = lane; k < DIM; k += 64) {
        float xv = xr[k];
        xb[k] = f2bf(xv);                // inline fp32->bf16 (row already read)
        const float* gp = gw + (size_t)k * NE;
        float4 g0 = *(const float4*)gp;
        float4 g1 = *(const float4*)(gp + 4);
        acc[0] += xv * g0.x; acc[1] += xv * g0.y;
        acc[2] += xv * g0.z; acc[3] += xv * g0.w;
        acc[4] += xv * g1.x; acc[5] += xv * g1.y;
        acc[6] += xv * g1.z; acc[7] += xv * g1.w;
    }
    #pragma unroll
    for (int e = 0; e < NE; e++) {
        #pragma unroll
        for (int off = 32; off > 0; off >>= 1)
            acc[e] += __shfl_down(acc[e], off, 64);
    }
    if (lane == 0) {
        float l[NE];
        float m = -1e30f;
        #pragma unroll
        for (int e = 0; e < NE; e++) { l[e] = acc[e] + gb[e]; m = fmaxf(m, l[e]); }
        float s = 0.f;
        #pragma unroll
        for (int e = 0; e < NE; e++) { l[e] = expf(l[e] - m); s += l[e]; }
        float inv = 1.f / s;
        int bi = 0; float bv = -1.f;
        #pragma unroll
        for (int e = 0; e < NE; e++) {
            float p = l[e] * inv;
            atomicAdd(&s_imp[e], p);             // LDS atomic
            if (p > bv) { bv = p; bi = e; }      // strict > => first argmax
        }
        top_val[t] = bv;
        top_idx[t] = bi;
        atomicAdd(&s_cnt[bi], 1);
    }
    __syncthreads();
    if (th < NE) {
        partial_imp[g * NE + th] = s_imp[th];
        partial_cnt[g * NE + th] = s_cnt[th];
    }
}

// ---------------------------------------------------------------------------
// Route (1 block, 256 thr): plan + scatter fused, LDS cursors (no memset).
// [verified R5/R10]
// ---------------------------------------------------------------------------
__global__ __launch_bounds__(256) void route_kernel(
    const float* __restrict__ partial_imp, const int* __restrict__ partial_cnt,
    const int* __restrict__ top_idx,
    int* __restrict__ sorted_tok,
    int* __restrict__ tile_e, int* __restrict__ tile_s,
    int* __restrict__ tile_rows, int* __restrict__ ntiles,
    float* __restrict__ loss_out)
{
    __shared__ float rimp[32][NE];
    __shared__ int   rcnt[32][NE];
    __shared__ int   s_off[NE];
    __shared__ int   s_cur[NE];
    const int th = threadIdx.x;
    const int e = th & 7, chunk = th >> 3;   // 32 chunks of 32 blocks
    float si = 0.f; int sc = 0;
    #pragma unroll 8
    for (int i = 0; i < GATE_BLOCKS / 32; i++) {
        const int b = chunk * (GATE_BLOCKS / 32) + i;
        si += partial_imp[b * NE + e];
        sc += partial_cnt[b * NE + e];
    }
    rimp[chunk][e] = si;
    rcnt[chunk][e] = sc;
    __syncthreads();
    if (th < NE) {
        float s = 0.f; int c = 0;
        for (int i = 0; i < 32; i++) { s += rimp[i][th]; c += rcnt[i][th]; }
        rimp[0][th] = s;
        rcnt[0][th] = c;
        s_cur[th] = 0;
    }
    __syncthreads();
    if (th == 0) {
        int off = 0, nt = 0;
        for (int ee = 0; ee < NE; ee++) {
            s_off[ee] = off;
            const int c = rcnt[0][ee];
            for (int s = 0; s < c; s += TMM) {
                tile_e[nt] = ee;
                tile_s[nt] = off + s;
                tile_rows[nt] = min(TMM, c - s);
                nt++;
            }
            off += c;
        }
        *ntiles = nt;   // <= 40

        float mean = 0.f;
        for (int ee = 0; ee < NE; ee++) mean += rimp[0][ee];
        mean *= (1.0f / NE);
        float var = 0.f;
        for (int ee = 0; ee < NE; ee++) { float d = rimp[0][ee] - mean; var += d * d; }
        var *= (1.0f / (NE - 1));
        loss_out[0] = var / (mean * mean + 1e-10f);
    }
    __syncthreads();
    // scatter: 16 rounds x 256 tokens, LDS cursors
    #pragma unroll 4
    for (int r = 0; r < T_TOK / 256; r++) {
        const int t  = r * 256 + th;
        const int te = top_idx[t];
        const int rank = atomicAdd(&s_cur[te], 1);
        sorted_tok[s_off[te] + rank] = t;
    }
}

// ---------------------------------------------------------------------------
// FFN1: MFMA 16x16x32, 128x256 tile, 512 thr / 8 waves (2M x 4N, each wave
// a 64x64 quadrant), SINGLE-buffer 48 KB LDS, XOR-swizzled staging.
// A rows gathered through sorted_tok (per-lane gld_lds src; verified R9).
// grid (40 tiles, 8 panels), TILE fastest (R1-vs-R4 A/B: ~25% better).
// ---------------------------------------------------------------------------
__global__ __launch_bounds__(512) void ffn1_mfma(
    const u16* __restrict__ xbf, const u16* __restrict__ w1t,
    const float* __restrict__ b1, const int* __restrict__ sorted_tok,
    const int* __restrict__ tile_e, const int* __restrict__ tile_s,
    const int* __restrict__ tile_rows, const int* __restrict__ ntiles,
    u16* __restrict__ h_buf)
{
    const int tile = blockIdx.x;
    if (tile >= *ntiles) return;
    const int e     = tile_e[tile];
    const int sbase = tile_s[tile];
    const int rows  = tile_rows[tile];
    const int nbase = blockIdx.y * 256;    // over HID, 8 panels

    __shared__ __align__(16) u16 As[128 * BK];   // 16 KB
    __shared__ __align__(16) u16 Bs[256 * BK];   // 32 KB

    const int th = threadIdx.x;
    const int w  = th >> 6;               // 0..7
    const int l  = th & 63;
    const int wm = w >> 2, wn = w & 3;    // 2M x 4N wave grid
    const int lr = l >> 3;                // 0..7 row in staging group
    const int lcs = ((l & 7) ^ lr) * 8;   // swizzled u16 fetch offset

    // A staging: 2 rounds; round c covers rows c*64 + w*8 + lr (indirect)
    const u16* aptr[2];
    #pragma unroll
    for (int c = 0; c < 2; c++) {
        int srow = sbase + c * 64 + w * 8 + lr;
        if (srow > T_TOK - 1) srow = T_TOK - 1;
        const int tok = sorted_tok[srow];
        aptr[c] = xbf + (size_t)tok * DIM + lcs;
    }
    // B staging: 4 rounds over 256 W1t rows
    const u16* wb = w1t + (size_t)e * HID * DIM + (size_t)nbase * DIM;
    const u16* bptr[4];
    #pragma unroll
    for (int c = 0; c < 4; c++)
        bptr[c] = wb + (size_t)(c * 64 + w * 8 + lr) * DIM + lcs;

    f32x4 acc[4][4] = {};

    for (int k0 = 0; k0 < DIM; k0 += BK) {
        __syncthreads();
        #pragma unroll
        for (int c = 0; c < 2; c++)
            gld_lds16(aptr[c] + k0, &As[(c * 64 + w * 8) * BK]);
        #pragma unroll
        for (int c = 0; c < 4; c++)
            gld_lds16(bptr[c] + k0, &Bs[(c * 64 + w * 8) * BK]);
        __syncthreads();
        #pragma unroll
        for (int ks = 0; ks < 2; ks++) {
            const int ko = ((ks * 4 + (l >> 4)) ^ (l & 7)) * 8;  // swizzled chunk
            bf16x8 af[4], bfr[4];
            #pragma unroll
            for (int i = 0; i < 4; i++)
                af[i]  = *(const bf16x8*)&As[(wm * 64 + i * 16 + (l & 15)) * BK + ko];
            #pragma unroll
            for (int i = 0; i < 4; i++)
                bfr[i] = *(const bf16x8*)&Bs[(wn * 64 + i * 16 + (l & 15)) * BK + ko];
            #pragma unroll
            for (int mi = 0; mi < 4; mi++)
                #pragma unroll
                for (int ni = 0; ni < 4; ni++)
                    acc[mi][ni] = __builtin_amdgcn_mfma_f32_16x16x32_bf16(
                        af[mi], bfr[ni], acc[mi][ni], 0, 0, 0);
        }
    }

    const int col = l & 15, quad = l >> 4;
    #pragma unroll
    for (int ni = 0; ni < 4; ni++) {
        const int n = nbase + wn * 64 + ni * 16 + col;
        const float bias = b1[e * HID + n];
        #pragma unroll
        for (int mi = 0; mi < 4; mi++) {
            #pragma unroll
            for (int r = 0; r < 4; r++) {
                const int m = wm * 64 + mi * 16 + quad * 4 + r;
                if (m < rows) {
                    float v = acc[mi][ni][r] + bias;
                    h_buf[(size_t)(sbase + m) * HID + n] = f2bf(gelu_fast(v));
                }
            }
        }
    }
}

// ---------------------------------------------------------------------------
// FFN2: MFMA 16x16x32, 128x128 tile, 256 thr / 4 waves, SINGLE-buffer 32 KB.
// grid (40 tiles, 8 panels), TILE fastest.  [verified R10]
// ---------------------------------------------------------------------------
__global__ __launch_bounds__(256) void ffn2_mfma(
    const u16* __restrict__ h_buf, const u16* __restrict__ w2t,
    const float* __restrict__ b2, const float* __restrict__ x,
    const int* __restrict__ sorted_tok, const float* __restrict__ top_val,
    const int* __restrict__ tile_e, const int* __restrict__ tile_s,
    const int* __restrict__ tile_rows, const int* __restrict__ ntiles,
    float* __restrict__ yout)
{
    const int tile = blockIdx.x;
    if (tile >= *ntiles) return;
    const int e     = tile_e[tile];
    const int sbase = tile_s[tile];
    const int rows  = tile_rows[tile];
    const int nbase = blockIdx.y * 128;    // over DIM, 8 panels

    __shared__ __align__(16) u16 As[128 * BK];
    __shared__ __align__(16) u16 Bs[128 * BK];

    const int th = threadIdx.x;
    const int w  = th >> 6;
    const int l  = th & 63;
    const int wm = w >> 1, wn = w & 1;
    const int lr = l >> 3;
    const int lcs = ((l & 7) ^ lr) * 8;

    const u16* aptr[4];
    #pragma unroll
    for (int c = 0; c < 4; c++) {
        int srow = sbase + w * 32 + c * 8 + lr;
        if (srow > T_TOK - 1) srow = T_TOK - 1;
        aptr[c] = h_buf + (size_t)srow * HID + lcs;
    }
    const u16* wb = w2t + (size_t)e * DIM * HID + (size_t)nbase * HID;
    const u16* bptr[4];
    #pragma unroll
    for (int c = 0; c < 4; c++)
        bptr[c] = wb + (size_t)(w * 32 + c * 8 + lr) * HID + lcs;

    f32x4 acc[4][4] = {};

    for (int k0 = 0; k0 < HID; k0 += BK) {
        __syncthreads();
        #pragma unroll
        for (int c = 0; c < 4; c++)
            gld_lds16(aptr[c] + k0, &As[(w * 32 + c * 8) * BK]);
        #pragma unroll
        for (int c = 0; c < 4; c++)
            gld_lds16(bptr[c] + k0, &Bs[(w * 32 + c * 8) * BK]);
        __syncthreads();
        #pragma unroll
        for (int ks = 0; ks < 2; ks++) {
            const int ko = ((ks * 4 + (l >> 4)) ^ (l & 7)) * 8;
            bf16x8 af[4], bfr[4];
            #pragma unroll
            for (int i = 0; i < 4; i++)
                af[i]  = *(const bf16x8*)&As[(wm * 64 + i * 16 + (l & 15)) * BK + ko];
            #pragma unroll
            for (int i = 0; i < 4; i++)
                bfr[i] = *(const bf16x8*)&Bs[(wn * 64 + i * 16 + (l & 15)) * BK + ko];
            #pragma unroll
            for (int mi = 0; mi < 4; mi++)
                #pragma unroll
                for (int ni = 0; ni < 4; ni++)
                    acc[mi][ni] = __builtin_amdgcn_mfma_f32_16x16x32_bf16(
                        af[mi], bfr[ni], acc[mi][ni], 0, 0, 0);
        }
    }

    const int col = l & 15, quad = l >> 4;
    float bias[4];
    #pragma unroll
    for (int ni = 0; ni < 4; ni++)
        bias[ni] = b2[e * DIM + nbase + wn * 64 + ni * 16 + col];

    #pragma unroll
    for (int mi = 0; mi < 4; mi++) {
        #pragma unroll
        for (int r = 0; r < 4; r++) {
            const int m = wm * 64 + mi * 16 + quad * 4 + r;
            if (m < rows) {
                const int t = sorted_tok[sbase + m];
                const float tv = top_val[t];
                #pragma unroll
                for (int ni = 0; ni < 4; ni++) {
                    const int n = nbase + wn * 64 + ni * 16 + col;
                    float v = acc[mi][ni][r] + bias[ni];
                    yout[(size_t)t * DIM + n] = x[(size_t)t * DIM + n] + v * tv;
                }
            }
        }
    }
}

// ---------------------------------------------------------------------------
// RMSNorm (F.normalize * gamma * sqrt(D)) + exact GeLU, in place.
// ---------------------------------------------------------------------------
__global__ __launch_bounds__(256) void norm_kernel(float* __restrict__ y,
                                                   const float* __restrict__ gamma)
{
    const int t = blockIdx.x;
    float* row = y + (size_t)t * DIM;
    const int th = threadIdx.x;
    float4 v = *(const float4*)&row[th * 4];
    float ss = v.x * v.x + v.y * v.y + v.z * v.z + v.w * v.w;

    const int lane = th & 63, wave = th >> 6;
    #pragma unroll
    for (int off = 32; off > 0; off >>= 1) ss += __shfl_down(ss, off, 64);
    __shared__ float red[4];
    if (lane == 0) red[wave] = ss;
    __syncthreads();
    float total = red[0] + red[1] + red[2] + red[3];

    float nrm = sqrtf(total);
    float scale = 32.0f / fmaxf(nrm, 1e-12f);   // sqrt(1024) = 32

    float4 g = *(const float4*)&gamma[th * 4];
    float4 o;
    o.x = gelu_exact(v.x * scale * g.x);
    o.y = gelu_exact(v.y * scale * g.y);
    o.z = gelu_exact(v.z * scale * g.z);
    o.w = gelu_exact(v.w * scale * g.w);
    *(float4*)&row[th * 4] = o;
}

// ---------------------------------------------------------------------------
extern "C" void kernel_launch(void* const* d_in, const int* in_sizes, int n_in,
                              void* d_out, int out_size, void* d_ws, size_t ws_size,
                              hipStream_t stream) {
    const float* x      = (const float*)d_in[0];
    const float* gate_w = (const float*)d_in[1];
    const float* gate_b = (const float*)d_in[2];
    const float* w1     = (const float*)d_in[3];
    const float* b1     = (const float*)d_in[4];
    const float* w2     = (const float*)d_in[5];
    const float* b2     = (const float*)d_in[6];
    const float* gamma  = (const float*)d_in[7];

    float* out  = (float*)d_out;                  // [T*D] y, then [1] loss
    float* loss = out + (size_t)T_TOK * DIM;

    char* ws = (char*)d_ws;
    float* top_val     = (float*)(ws + 0);         // 4096 f
    int*   top_idx     = (int*)  (ws + 16384);     // 4096 i
    int*   sorted_tok  = (int*)  (ws + 32768);     // 4096 i
    int*   tile_e      = (int*)  (ws + 49664);     // 40 i
    int*   tile_s      = (int*)  (ws + 50176);     // 40 i
    int*   tile_rows   = (int*)  (ws + 50688);     // 40 i
    int*   ntiles      = (int*)  (ws + 51200);     // 1 i
    float* partial_imp = (float*)(ws + 65536);     // 1024*8 f = 32 KB
    int*   partial_cnt = (int*)  (ws + 98304);     // 1024*8 i = 32 KB
    u16*   xbf         = (u16*)  (ws + 131072);                      // 8 MiB
    u16*   h_buf       = (u16*)  (ws + 131072 + 8388608);            // 16 MiB
    u16*   w1t         = (u16*)  (ws + 131072 + 8388608 + 16777216);            // 32 MiB
    u16*   w2t         = (u16*)  (ws + 131072 + 8388608 + 16777216 + 33554432); // 32 MiB

    // fused transposes (64x128 reg-staged) + gate w/ inline x->bf16
    prep_kernel<<<PREP_IDS, 256, 0, stream>>>(
        w1, w2, w1t, w2t, x, gate_w, gate_b, xbf, top_val, top_idx,
        partial_imp, partial_cnt);
    // plan + scatter fused, single block (LDS cursors -> no memset)
    route_kernel<<<1, 256, 0, stream>>>(partial_imp, partial_cnt, top_idx,
                                        sorted_tok, tile_e, tile_s, tile_rows,
                                        ntiles, loss);

    // TILE-fastest grids; ffn1 A rows via sorted_tok indirection (no gather)
    ffn1_mfma<<<dim3(40, HID / 256), 512, 0, stream>>>(
        xbf, w1t, b1, sorted_tok, tile_e, tile_s, tile_rows, ntiles, h_buf);
    ffn2_mfma<<<dim3(40, DIM / 128), 256, 0, stream>>>(
        h_buf, w2t, b2, x, sorted_tok, top_val, tile_e, tile_s, tile_rows,
        ntiles, out);
    norm_kernel<<<T_TOK, 256, 0, stream>>>(out, gamma);
}